// Round 3
// baseline (717.245 us; speedup 1.0000x reference)
//
#include <hip/hip_runtime.h>
#include <stdint.h>

#define N_TOK 7200
#define N_PAD 7232      // old fp32 z padding (113*64)
#define N_PAD_A 7296    // 57*128, dpass A-tile row padding
#define K_CODE 8912
#define K_PAD 8960      // 140*64 = 70*128
#define N_KT 140        // 64-col half-tiles (combine granularity, unchanged)
#define NKT128 70       // 128-col dpass tiles
#define NMT128 57       // 128-row dpass tiles
#define MID 256
#define C_DIM 768
#define INV_TEMP (1.0f/0.07f)
#define INV_ETEMP 100.0f
#define MARGIN 0.02f
#define CAND_CAP 64
#define EPS_N 1e-12f

typedef __attribute__((ext_vector_type(8))) short short8;   // 8 bf16 (4 VGPRs)
typedef __attribute__((ext_vector_type(4))) float f32x4;

__device__ __forceinline__ unsigned short f2bf(float f) {
    unsigned u = __float_as_uint(f);
    u += 0x7fffu + ((u >> 16) & 1u);   // round-to-nearest-even
    return (unsigned short)(u >> 16);
}
__device__ __forceinline__ float bf2f(unsigned short h) {
    return __uint_as_float(((unsigned)h) << 16);
}

// async global->LDS, 16B per lane; LDS dest = wave-uniform base + lane*16
__device__ __forceinline__ void gload16(const void* g, void* l) {
    __builtin_amdgcn_global_load_lds(
        (const __attribute__((address_space(1))) unsigned int*)g,
        (__attribute__((address_space(3))) unsigned int*)l,
        16, 0, 0);
}

// ---------------- fused prep: ennorm | wsplit | init ------------------------
__global__ void k_prep(const float* __restrict__ emb,
                       float* __restrict__ en, unsigned short* __restrict__ en_h,
                       const float* __restrict__ W,
                       unsigned short* __restrict__ wt_h, unsigned short* __restrict__ wt_l,
                       float* __restrict__ ap_acc, int* __restrict__ used,
                       float* __restrict__ acc4, int* __restrict__ ccnt,
                       unsigned short* __restrict__ zn_h) {
    __shared__ float sb[256];
    int b = blockIdx.x, t = threadIdx.x;
    if (b < K_CODE) {
        float v = emb[b * MID + t];
        sb[t] = v * v; __syncthreads();
        for (int s = 128; s > 0; s >>= 1) { if (t < s) sb[t] += sb[t + s]; __syncthreads(); }
        float nn = sqrtf(sb[0]);
        float o = v / fmaxf(nn, EPS_N);
        en[b * MID + t] = o;
        en_h[b * MID + t] = f2bf(o);
    } else if (b < K_CODE + 768) {
        int i = (b - K_CODE) * 256 + t;       // < C_DIM*MID exactly
        int c = i / MID, tc = i % MID;
        float v = W[i];
        unsigned short h = f2bf(v);
        unsigned short l = f2bf(v - bf2f(h));
        wt_h[tc * C_DIM + c] = h;
        wt_l[tc * C_DIM + c] = l;
    } else {
        int i = (b - K_CODE - 768) * 256 + t;  // 0..8959
        if (i < K_CODE) { ap_acc[i] = 0.f; used[i] = 0; }
        if (i < N_TOK) ccnt[i] = 0;
        if (i < 4) acc4[i] = 0.f;
        for (int j = i; j < (N_PAD_A - N_TOK) * MID; j += 8960) zn_h[(size_t)N_TOK * MID + j] = 0;
        for (int j = i; j < (K_PAD - K_CODE) * MID; j += 8960) en_h[(size_t)K_CODE * MID + j] = 0;
    }
}

// ---------------- z = x @ W_down via bf16x3 MFMA (fp32-quality) -------------
__global__ __launch_bounds__(256) void k_zgemm(const float* __restrict__ x,
                                               const unsigned short* __restrict__ wt_h,
                                               const unsigned short* __restrict__ wt_l,
                                               float* __restrict__ zbuf) {
    __shared__ unsigned short ls[4 * 64 * 72];
    unsigned short* xh = ls;
    unsigned short* xl = ls + 64 * 72;
    unsigned short* wh = ls + 2 * 64 * 72;
    unsigned short* wl = ls + 3 * 64 * 72;
    int tid = threadIdx.x;
    int m0 = blockIdx.y * 64;
    int t0 = blockIdx.x * 64;
    int lane = tid & 63, wv = tid >> 6;
    int quad = lane >> 4, l15 = lane & 15;
    int mrow0 = (wv >> 1) * 32, ncol0 = (wv & 1) * 32;
    f32x4 acc[2][2] = {};

    for (int ch = 0; ch < 12; ch++) {
        int c0 = ch * 64;
        for (int it = 0; it < 4; it++) {
            int r = it * 16 + (tid >> 4);
            int cq = tid & 15;
            float4 v = make_float4(0.f, 0.f, 0.f, 0.f);
            int gr = m0 + r;
            if (gr < N_TOK) v = ((const float4*)x)[(size_t)gr * (C_DIM / 4) + (c0 >> 2) + cq];
            unsigned short h0 = f2bf(v.x), h1 = f2bf(v.y), h2 = f2bf(v.z), h3 = f2bf(v.w);
            ushort4 hh = make_ushort4(h0, h1, h2, h3);
            ushort4 ll = make_ushort4(f2bf(v.x - bf2f(h0)), f2bf(v.y - bf2f(h1)),
                                      f2bf(v.z - bf2f(h2)), f2bf(v.w - bf2f(h3)));
            *((ushort4*)&xh[r * 72 + cq * 4]) = hh;
            *((ushort4*)&xl[r * 72 + cq * 4]) = ll;
        }
        for (int it = 0; it < 2; it++) {
            int r = it * 32 + (tid >> 3);
            int cq = tid & 7;
            uint4 vh = ((const uint4*)wt_h)[(size_t)(t0 + r) * (C_DIM / 8) + (c0 >> 3) + cq];
            uint4 vl = ((const uint4*)wt_l)[(size_t)(t0 + r) * (C_DIM / 8) + (c0 >> 3) + cq];
            *((uint4*)&wh[r * 72 + cq * 8]) = vh;
            *((uint4*)&wl[r * 72 + cq * 8]) = vl;
        }
        __syncthreads();
        for (int ks = 0; ks < 2; ks++) {
            int co = ks * 32 + quad * 8;
            short8 ah0 = *((const short8*)&xh[(mrow0 + l15) * 72 + co]);
            short8 ah1 = *((const short8*)&xh[(mrow0 + 16 + l15) * 72 + co]);
            short8 al0 = *((const short8*)&xl[(mrow0 + l15) * 72 + co]);
            short8 al1 = *((const short8*)&xl[(mrow0 + 16 + l15) * 72 + co]);
            short8 bh0 = *((const short8*)&wh[(ncol0 + l15) * 72 + co]);
            short8 bh1 = *((const short8*)&wh[(ncol0 + 16 + l15) * 72 + co]);
            short8 bl0 = *((const short8*)&wl[(ncol0 + l15) * 72 + co]);
            short8 bl1 = *((const short8*)&wl[(ncol0 + 16 + l15) * 72 + co]);
            acc[0][0] = __builtin_amdgcn_mfma_f32_16x16x32_bf16(ah0, bh0, acc[0][0], 0, 0, 0);
            acc[0][1] = __builtin_amdgcn_mfma_f32_16x16x32_bf16(ah0, bh1, acc[0][1], 0, 0, 0);
            acc[1][0] = __builtin_amdgcn_mfma_f32_16x16x32_bf16(ah1, bh0, acc[1][0], 0, 0, 0);
            acc[1][1] = __builtin_amdgcn_mfma_f32_16x16x32_bf16(ah1, bh1, acc[1][1], 0, 0, 0);
            acc[0][0] = __builtin_amdgcn_mfma_f32_16x16x32_bf16(ah0, bl0, acc[0][0], 0, 0, 0);
            acc[0][1] = __builtin_amdgcn_mfma_f32_16x16x32_bf16(ah0, bl1, acc[0][1], 0, 0, 0);
            acc[1][0] = __builtin_amdgcn_mfma_f32_16x16x32_bf16(ah1, bl0, acc[1][0], 0, 0, 0);
            acc[1][1] = __builtin_amdgcn_mfma_f32_16x16x32_bf16(ah1, bl1, acc[1][1], 0, 0, 0);
            acc[0][0] = __builtin_amdgcn_mfma_f32_16x16x32_bf16(al0, bh0, acc[0][0], 0, 0, 0);
            acc[0][1] = __builtin_amdgcn_mfma_f32_16x16x32_bf16(al0, bh1, acc[0][1], 0, 0, 0);
            acc[1][0] = __builtin_amdgcn_mfma_f32_16x16x32_bf16(al1, bh0, acc[1][0], 0, 0, 0);
            acc[1][1] = __builtin_amdgcn_mfma_f32_16x16x32_bf16(al1, bh1, acc[1][1], 0, 0, 0);
        }
        __syncthreads();
    }
    for (int i = 0; i < 2; i++)
        for (int j = 0; j < 2; j++)
            for (int r = 0; r < 4; r++) {
                int gr = m0 + mrow0 + i * 16 + quad * 4 + r;
                int gc = t0 + ncol0 + j * 16 + l15;
                if (gr < N_TOK) zbuf[(size_t)gr * MID + gc] = acc[i][j][r];
            }
}

// ---------------- z + b -> l2norm -> zn (in place) + zn_h -------------------
__global__ void k_znorm(float* __restrict__ zbuf, const float* __restrict__ b_down,
                        unsigned short* __restrict__ zn_h) {
    int n = blockIdx.x, t = threadIdx.x;
    float v = zbuf[(size_t)n * MID + t] + b_down[t];
    __shared__ float sb[256];
    sb[t] = v * v; __syncthreads();
    for (int s = 128; s > 0; s >>= 1) { if (t < s) sb[t] += sb[t + s]; __syncthreads(); }
    float nn = sqrtf(sb[0]);
    float o = v / fmaxf(nn, EPS_N);
    zbuf[(size_t)n * MID + t] = o;
    zn_h[(size_t)n * MID + t] = f2bf(o);
}

// ---------------- SINGLE d-GEMM: part4 stats + raw d (f32) -> out1 ----------
// 128x128 tile, single-buffered 32 KiB LDS, global_load_lds width-16 staging,
// XOR-swizzled columns via pre-swizzled global source (rule 21).
__global__ __launch_bounds__(256) void k_dgemm(const unsigned short* __restrict__ zn_h,
                                               const unsigned short* __restrict__ en_h,
                                               float4* __restrict__ part4,
                                               float* __restrict__ out1) {
    __shared__ __align__(16) char lds[32768];   // A[128][64] + B[128][64] bf16
    int tid = threadIdx.x;
    // XCD-bijective swizzle, kt-major: each XCD owns a contiguous kt range.
    int flat = blockIdx.x * NMT128 + blockIdx.y;
    const int NW = NKT128 * NMT128;                  // 3990
    const int q = NW >> 3, r8 = NW & 7;              // 498, 6
    int xcd = flat & 7, sidx = flat >> 3;
    int wg = (xcd < r8 ? xcd * (q + 1) : r8 * (q + 1) + (xcd - r8) * q) + sidx;
    int kt = wg / NMT128, mt = wg - kt * NMT128;
    int m0 = mt * 128, k0 = kt * 128;
    int lane = tid & 63, wv = tid >> 6;
    int quad = lane >> 4, l15 = lane & 15;
    int wr = wv >> 1, wc = wv & 1;          // wave sub-tile: rows wr*64, cols wc*64
    f32x4 acc[4][4] = {};

    int sr = tid >> 3;                      // staging row within 32-row group
    int scb = (tid & 7) * 16;               // dest col byte (0..112)

    for (int step = 0; step < 4; step++) {
        int cB = step * 128;                // global byte offset within row
        #pragma unroll
        for (int it = 0; it < 4; it++) {
            int r = it * 32 + sr;
            int srcb = scb ^ ((r & 7) << 4);     // pre-swizzled source column
            gload16((const char*)zn_h + (size_t)(m0 + r) * 512 + cB + srcb,
                    lds + it * 4096 + wv * 1024);
            gload16((const char*)en_h + (size_t)(k0 + r) * 512 + cB + srcb,
                    lds + 16384 + it * 4096 + wv * 1024);
        }
        __syncthreads();
        #pragma unroll
        for (int ks = 0; ks < 2; ks++) {
            short8 a[4], b[4];
            #pragma unroll
            for (int i = 0; i < 4; i++) {
                int ra = wr * 64 + i * 16 + l15;
                int ca = (ks * 64 + quad * 16) ^ ((ra & 7) << 4);
                a[i] = *(const short8*)(lds + ra * 128 + ca);
                int rb = wc * 64 + i * 16 + l15;
                int cb2 = (ks * 64 + quad * 16) ^ ((rb & 7) << 4);
                b[i] = *(const short8*)(lds + 16384 + rb * 128 + cb2);
            }
            #pragma unroll
            for (int i = 0; i < 4; i++)
                #pragma unroll
                for (int j = 0; j < 4; j++)
                    acc[i][j] = __builtin_amdgcn_mfma_f32_16x16x32_bf16(a[i], b[j], acc[i][j], 0, 0, 0);
        }
        __syncthreads();
    }

    // epilogue: d store (f32 -> out1) + per-64-col-half stats -> part4
    int kth = kt * 2 + wc;                  // 64-col half index, 0..139
    #pragma unroll
    for (int i = 0; i < 4; i++) {
        #pragma unroll
        for (int r = 0; r < 4; r++) {
            int gr = m0 + wr * 64 + i * 16 + quad * 4 + r;
            bool okr = gr < N_TOK;
            float dv[4]; float vmin = 1e30f;
            #pragma unroll
            for (int j = 0; j < 4; j++) {
                int gc = k0 + wc * 64 + j * 16 + l15;
                float d = 2.f - 2.f * acc[i][j][r];
                bool okc = gc < K_CODE;
                dv[j] = okc ? d : 1e30f;
                vmin = fminf(vmin, dv[j]);
                if (okr && okc) out1[(size_t)gr * K_CODE + gc] = d;
            }
            vmin = fminf(vmin, __shfl_xor(vmin, 1));
            vmin = fminf(vmin, __shfl_xor(vmin, 2));
            vmin = fminf(vmin, __shfl_xor(vmin, 4));
            vmin = fminf(vmin, __shfl_xor(vmin, 8));
            float st = 0.f, s1 = 0.f, s2 = 0.f;
            #pragma unroll
            for (int j = 0; j < 4; j++) {
                float dd = vmin - dv[j];         // <=0; masked: -1e30 -> exp=0
                st += __expf(dd * INV_TEMP);
                float te = dd * INV_ETEMP;
                float e = __expf(te);
                s1 += e; s2 += e * te;
            }
            st += __shfl_xor(st, 1); st += __shfl_xor(st, 2);
            st += __shfl_xor(st, 4); st += __shfl_xor(st, 8);
            s1 += __shfl_xor(s1, 1); s1 += __shfl_xor(s1, 2);
            s1 += __shfl_xor(s1, 4); s1 += __shfl_xor(s1, 8);
            s2 += __shfl_xor(s2, 1); s2 += __shfl_xor(s2, 2);
            s2 += __shfl_xor(s2, 4); s2 += __shfl_xor(s2, 8);
            if (l15 == 0 && okr) {
                part4[(size_t)gr * N_KT + kth] = make_float4(vmin, st, s1, s2);
            }
        }
    }
}

// ---------------- combine 140 tile-partials per row -------------------------
__global__ void k_combine(const float4* __restrict__ part4,
                          float* __restrict__ rs_m, float* __restrict__ rs_ist,
                          float* __restrict__ rs_is1,
                          float* __restrict__ acc4) {
    int sub = threadIdx.x >> 6;
    int row = blockIdx.x * 4 + sub;
    int l = threadIdx.x & 63;
    float4 pv[3];
    float m = 1e30f;
    #pragma unroll
    for (int c = 0; c < 3; c++) {
        int t = l + c * 64;
        pv[c] = (t < N_KT) ? part4[(size_t)row * N_KT + t] : make_float4(1e30f, 0.f, 0.f, 0.f);
        m = fminf(m, pv[c].x);
    }
    #pragma unroll
    for (int s = 1; s < 64; s <<= 1) m = fminf(m, __shfl_xor(m, s));
    float st = 0.f, s1 = 0.f, s2 = 0.f;
    #pragma unroll
    for (int c = 0; c < 3; c++) {
        float mb = pv[c].x;
        int t = l + c * 64;
        if (t < N_KT && mb < 1e29f) {
            float dT = (m - mb) * INV_TEMP;
            st += __expf(dT) * pv[c].y;
            float dE = (m - mb) * INV_ETEMP;
            float e = __expf(dE);
            s1 += e * pv[c].z;
            s2 += e * (pv[c].w + dE * pv[c].z);
        }
    }
    #pragma unroll
    for (int s = 1; s < 64; s <<= 1) {
        st += __shfl_xor(st, s);
        s1 += __shfl_xor(s1, s);
        s2 += __shfl_xor(s2, s);
    }
    if (l == 0) {
        rs_m[row] = m;
        rs_ist[row] = 1.f / st;
        rs_is1[row] = 1.f / s1;
        atomicAdd(&acc4[1], s2 / s1 - __logf(s1));
    }
}

// ---------------- streaming finalize: d -> p in place + col sums + cands ----
// block tile: 128 rows x 256 cols; thread t: row-group t>>6 (32 rows), cols 4*(t&63)
__global__ __launch_bounds__(256) void k_final(float* __restrict__ out1,
                                               const float* __restrict__ rs_m,
                                               const float* __restrict__ rs_ist,
                                               const float* __restrict__ rs_is1,
                                               float* __restrict__ ap_acc,
                                               int* __restrict__ ccnt,
                                               int* __restrict__ cand) {
    __shared__ float lm[128], lt_[128], l1_[128];
    __shared__ float colacc[4 * 256];
    int ct = blockIdx.x, rt = blockIdx.y;
    int r0 = rt * 128, c0 = ct * 256;
    int t = threadIdx.x;
    if (t < 128) {
        int gr = r0 + t;
        bool ok = gr < N_TOK;
        lm[t]  = ok ? rs_m[gr]   : 0.f;
        lt_[t] = ok ? rs_ist[gr] : 0.f;
        l1_[t] = ok ? rs_is1[gr] : 0.f;
    }
    __syncthreads();
    int g = t >> 6;
    int cq = (t & 63) * 4;
    int gc = c0 + cq;
    float ce0 = 0.f, ce1 = 0.f, ce2 = 0.f, ce3 = 0.f;
    if (gc < K_CODE) {                      // K_CODE%4==0: float4 fully valid
        for (int i = 0; i < 32; i++) {
            int lr = g * 32 + i;
            int gr = r0 + lr;
            if (gr >= N_TOK) break;
            size_t base = (size_t)gr * K_CODE + gc;
            float4 d = *(const float4*)(out1 + base);
            float m_ = lm[lr], tt = lt_[lr], i1 = l1_[lr];
            float thr = m_ + MARGIN;
            ce0 += __expf((m_ - d.x) * INV_ETEMP) * i1;
            ce1 += __expf((m_ - d.y) * INV_ETEMP) * i1;
            ce2 += __expf((m_ - d.z) * INV_ETEMP) * i1;
            ce3 += __expf((m_ - d.w) * INV_ETEMP) * i1;
            float4 p;
            p.x = __expf((m_ - d.x) * INV_TEMP) * tt;
            p.y = __expf((m_ - d.y) * INV_TEMP) * tt;
            p.z = __expf((m_ - d.z) * INV_TEMP) * tt;
            p.w = __expf((m_ - d.w) * INV_TEMP) * tt;
            *((float4*)(out1 + base)) = p;
            if (d.x <= thr) { int pd = atomicAdd(&ccnt[gr], 1); if (pd < CAND_CAP) cand[gr * CAND_CAP + pd] = gc + 0; }
            if (d.y <= thr) { int pd = atomicAdd(&ccnt[gr], 1); if (pd < CAND_CAP) cand[gr * CAND_CAP + pd] = gc + 1; }
            if (d.z <= thr) { int pd = atomicAdd(&ccnt[gr], 1); if (pd < CAND_CAP) cand[gr * CAND_CAP + pd] = gc + 2; }
            if (d.w <= thr) { int pd = atomicAdd(&ccnt[gr], 1); if (pd < CAND_CAP) cand[gr * CAND_CAP + pd] = gc + 3; }
        }
    }
    colacc[g * 256 + cq + 0] = ce0;
    colacc[g * 256 + cq + 1] = ce1;
    colacc[g * 256 + cq + 2] = ce2;
    colacc[g * 256 + cq + 3] = ce3;
    __syncthreads();
    {
        float s = colacc[t] + colacc[256 + t] + colacc[512 + t] + colacc[768 + t];
        int c = c0 + t;
        if (c < K_CODE) atomicAdd(&ap_acc[c], s);
    }
}

// ---------------- exact fp32 argmin over candidates + out0 fused ------------
__global__ void k_refine(const float* __restrict__ zn, const float* __restrict__ en,
                         const int* __restrict__ ccnt, const int* __restrict__ cand,
                         int* __restrict__ idxb, int* __restrict__ used,
                         float* __restrict__ acc4, float* __restrict__ out0) {
    int n = blockIdx.x * 4 + (threadIdx.x >> 6);
    int lane = threadIdx.x & 63;
    if (n >= N_TOK) return;
    int cnt = ccnt[n];
    if (cnt > CAND_CAP) cnt = CAND_CAP;
    float4 a = ((const float4*)(zn + (size_t)n * MID))[lane];
    float best = 1e30f; int bj = K_CODE;
    for (int c = 0; c < cnt; c++) {
        int code = cand[n * CAND_CAP + c];
        float4 b = ((const float4*)(en + (size_t)code * MID))[lane];
        float s = a.x * b.x + a.y * b.y + a.z * b.z + a.w * b.w;
        #pragma unroll
        for (int off = 1; off < 64; off <<= 1) s += __shfl_xor(s, off);
        float dist = 2.f - 2.f * s;
        if (dist < best || (dist == best && code < bj)) { best = dist; bj = code; }
    }
    float4 b = ((const float4*)(en + (size_t)bj * MID))[lane];
    ((float4*)(out0 + (size_t)n * MID))[lane] = b;      // z_q_ste row = en[bj]
    float dx = b.x - a.x, dy = b.y - a.y, dz = b.z - a.z, dw = b.w - a.w;
    float sq = dx * dx + dy * dy + dz * dz + dw * dw;
    #pragma unroll
    for (int off = 32; off > 0; off >>= 1) sq += __shfl_down(sq, off);
    if (lane == 0) {
        idxb[n] = bj;
        used[bj] = 1;
        atomicAdd(&acc4[0], sq);
    }
}

// ---------------- final scalars ---------------------------------------------
__global__ void k_scal(const int* __restrict__ used, const float* __restrict__ ap_acc,
                       const float* __restrict__ acc4, float* __restrict__ outs) {
    int t = threadIdx.x;
    float uSum = 0.f, aeSum = 0.f;
    for (int k = t; k < K_CODE; k += 256) {
        uSum += (float)used[k];
        float ap = ap_acc[k] * (1.0f / (float)N_TOK);
        aeSum += ap * __logf(ap + 1e-5f);
    }
    __shared__ float sb[256];
    sb[t] = uSum; __syncthreads();
    for (int s = 128; s > 0; s >>= 1) { if (t < s) sb[t] += sb[t + s]; __syncthreads(); }
    uSum = sb[0];
    __syncthreads(); sb[t] = aeSum; __syncthreads();
    for (int s = 128; s > 0; s >>= 1) { if (t < s) sb[t] += sb[t + s]; __syncthreads(); }
    aeSum = sb[0];
    if (t == 0) {
        outs[0] = uSum / (float)K_CODE;
        float vq = acc4[0] / (float)((size_t)N_TOK * MID);
        outs[1] = vq;
        outs[2] = vq;
        outs[3] = -(acc4[1] / (float)N_TOK) + aeSum;
    }
}

extern "C" void kernel_launch(void* const* d_in, const int* in_sizes, int n_in,
                              void* d_out, int out_size, void* d_ws, size_t ws_size,
                              hipStream_t stream) {
    const float* x   = (const float*)d_in[0];
    const float* W   = (const float*)d_in[1];
    const float* b   = (const float*)d_in[2];
    const float* emb = (const float*)d_in[3];

    float* out  = (float*)d_out;
    float* out0 = out;                                                  // [7200*256]
    float* out1 = out + (size_t)N_TOK * MID;                            // probs (d-scratch first)
    float* outs = out + (size_t)N_TOK * MID + (size_t)N_TOK * K_CODE;   // 4 scalars

    char* w = (char*)d_ws;
    size_t off = 0;
    auto carve = [&](size_t bytes) { void* p = w + off; off += (bytes + 255) & ~(size_t)255; return p; };
    float*          zn    = (float*)         carve((size_t)N_PAD * MID * 4);
    float*          en    = (float*)         carve((size_t)K_PAD * MID * 4);
    unsigned short* zn_h  = (unsigned short*)carve((size_t)N_PAD_A * MID * 2);
    unsigned short* en_h  = (unsigned short*)carve((size_t)K_PAD * MID * 2);
    unsigned short* wt_h  = (unsigned short*)carve((size_t)MID * C_DIM * 2);
    unsigned short* wt_l  = (unsigned short*)carve((size_t)MID * C_DIM * 2);
    float4*         part4 = (float4*)        carve((size_t)N_TOK * N_KT * 16);
    float*          rs_m  = (float*)         carve((size_t)N_TOK * 4);
    float*          rs_ist= (float*)         carve((size_t)N_TOK * 4);
    float*          rs_is1= (float*)         carve((size_t)N_TOK * 4);
    int*            ccnt  = (int*)           carve((size_t)N_TOK * 4);
    int*            cand  = (int*)           carve((size_t)N_TOK * CAND_CAP * 4);
    int*            idxb  = (int*)           carve((size_t)N_TOK * 4);
    float*          ap_acc= (float*)         carve((size_t)K_CODE * 4);
    int*            used  = (int*)           carve((size_t)K_CODE * 4);
    float*          acc4  = (float*)         carve(16);
    (void)ws_size; (void)in_sizes; (void)n_in; (void)out_size;

    k_prep   <<<K_CODE + 768 + 35, 256, 0, stream>>>(emb, en, en_h, W, wt_h, wt_l,
                                                     ap_acc, used, acc4, ccnt, zn_h);
    k_zgemm  <<<dim3(4, 113), 256, 0, stream>>>(x, wt_h, wt_l, zn);
    k_znorm  <<<N_TOK, 256, 0, stream>>>(zn, b, zn_h);
    k_dgemm  <<<dim3(NKT128, NMT128), 256, 0, stream>>>(zn_h, en_h, part4, out1);
    k_combine<<<N_TOK / 4, 256, 0, stream>>>(part4, rs_m, rs_ist, rs_is1, acc4);
    k_final  <<<dim3(35, 57), 256, 0, stream>>>(out1, rs_m, rs_ist, rs_is1, ap_acc, ccnt, cand);
    k_refine <<<N_TOK / 4, 256, 0, stream>>>(zn, en, ccnt, cand, idxb, used, acc4, out0);
    k_scal   <<<1, 256, 0, stream>>>(used, ap_acc, acc4, outs);
}

// Round 4
// 694.444 us; speedup vs baseline: 1.0328x; 1.0328x over previous
//
#include <hip/hip_runtime.h>
#include <stdint.h>

#define N_TOK 7200
#define N_PAD 7232      // fp32 z padding (113*64)
#define N_PAD_A 7296    // 57*128, dpass A-tile row padding
#define K_CODE 8912
#define K_PAD 8960      // 140*64 = 70*128
#define N_KT 140        // 64-col half-tiles (combine granularity)
#define NKT128 70       // 128-col dpass tiles
#define NMT128 57       // 128-row dpass tiles
#define MID 256
#define C_DIM 768
#define INV_TEMP (1.0f/0.07f)
#define INV_ETEMP 100.0f
#define MARGIN 0.02f
#define CAND_CAP 64
#define EPS_N 1e-12f

typedef __attribute__((ext_vector_type(8))) short short8;   // 8 bf16 (4 VGPRs)
typedef __attribute__((ext_vector_type(4))) float f32x4;

__device__ __forceinline__ unsigned short f2bf(float f) {
    unsigned u = __float_as_uint(f);
    u += 0x7fffu + ((u >> 16) & 1u);   // round-to-nearest-even
    return (unsigned short)(u >> 16);
}
__device__ __forceinline__ float bf2f(unsigned short h) {
    return __uint_as_float(((unsigned)h) << 16);
}

// async global->LDS, 16B per lane; LDS dest = wave-uniform base + lane*16
__device__ __forceinline__ void gload16(const void* g, void* l) {
    __builtin_amdgcn_global_load_lds(
        (const __attribute__((address_space(1))) unsigned int*)g,
        (__attribute__((address_space(3))) unsigned int*)l,
        16, 0, 0);
}

// ---------------- fused prep: ennorm | wsplit | init ------------------------
__global__ void k_prep(const float* __restrict__ emb,
                       float* __restrict__ en, unsigned short* __restrict__ en_h,
                       const float* __restrict__ W,
                       unsigned short* __restrict__ wt_h, unsigned short* __restrict__ wt_l,
                       float* __restrict__ ap_acc, int* __restrict__ used,
                       float* __restrict__ acc4, int* __restrict__ ccnt,
                       unsigned short* __restrict__ zn_h) {
    __shared__ float sb[256];
    int b = blockIdx.x, t = threadIdx.x;
    if (b < K_CODE) {
        float v = emb[b * MID + t];
        sb[t] = v * v; __syncthreads();
        for (int s = 128; s > 0; s >>= 1) { if (t < s) sb[t] += sb[t + s]; __syncthreads(); }
        float nn = sqrtf(sb[0]);
        float o = v / fmaxf(nn, EPS_N);
        en[b * MID + t] = o;
        en_h[b * MID + t] = f2bf(o);
    } else if (b < K_CODE + 768) {
        int i = (b - K_CODE) * 256 + t;       // < C_DIM*MID exactly
        int c = i / MID, tc = i % MID;
        float v = W[i];
        unsigned short h = f2bf(v);
        unsigned short l = f2bf(v - bf2f(h));
        wt_h[tc * C_DIM + c] = h;
        wt_l[tc * C_DIM + c] = l;
    } else {
        int i = (b - K_CODE - 768) * 256 + t;  // 0..8959
        if (i < K_CODE) { ap_acc[i] = 0.f; used[i] = 0; }
        if (i < N_TOK) ccnt[i] = 0;
        if (i < 4) acc4[i] = 0.f;
        for (int j = i; j < (N_PAD_A - N_TOK) * MID; j += 8960) zn_h[(size_t)N_TOK * MID + j] = 0;
        for (int j = i; j < (K_PAD - K_CODE) * MID; j += 8960) en_h[(size_t)K_CODE * MID + j] = 0;
    }
}

// ---------------- z = x @ W_down via bf16x3 MFMA (fp32-quality) -------------
__global__ __launch_bounds__(256) void k_zgemm(const float* __restrict__ x,
                                               const unsigned short* __restrict__ wt_h,
                                               const unsigned short* __restrict__ wt_l,
                                               float* __restrict__ zbuf) {
    __shared__ unsigned short ls[4 * 64 * 72];
    unsigned short* xh = ls;
    unsigned short* xl = ls + 64 * 72;
    unsigned short* wh = ls + 2 * 64 * 72;
    unsigned short* wl = ls + 3 * 64 * 72;
    int tid = threadIdx.x;
    int m0 = blockIdx.y * 64;
    int t0 = blockIdx.x * 64;
    int lane = tid & 63, wv = tid >> 6;
    int quad = lane >> 4, l15 = lane & 15;
    int mrow0 = (wv >> 1) * 32, ncol0 = (wv & 1) * 32;
    f32x4 acc[2][2] = {};

    for (int ch = 0; ch < 12; ch++) {
        int c0 = ch * 64;
        for (int it = 0; it < 4; it++) {
            int r = it * 16 + (tid >> 4);
            int cq = tid & 15;
            float4 v = make_float4(0.f, 0.f, 0.f, 0.f);
            int gr = m0 + r;
            if (gr < N_TOK) v = ((const float4*)x)[(size_t)gr * (C_DIM / 4) + (c0 >> 2) + cq];
            unsigned short h0 = f2bf(v.x), h1 = f2bf(v.y), h2 = f2bf(v.z), h3 = f2bf(v.w);
            ushort4 hh = make_ushort4(h0, h1, h2, h3);
            ushort4 ll = make_ushort4(f2bf(v.x - bf2f(h0)), f2bf(v.y - bf2f(h1)),
                                      f2bf(v.z - bf2f(h2)), f2bf(v.w - bf2f(h3)));
            *((ushort4*)&xh[r * 72 + cq * 4]) = hh;
            *((ushort4*)&xl[r * 72 + cq * 4]) = ll;
        }
        for (int it = 0; it < 2; it++) {
            int r = it * 32 + (tid >> 3);
            int cq = tid & 7;
            uint4 vh = ((const uint4*)wt_h)[(size_t)(t0 + r) * (C_DIM / 8) + (c0 >> 3) + cq];
            uint4 vl = ((const uint4*)wt_l)[(size_t)(t0 + r) * (C_DIM / 8) + (c0 >> 3) + cq];
            *((uint4*)&wh[r * 72 + cq * 8]) = vh;
            *((uint4*)&wl[r * 72 + cq * 8]) = vl;
        }
        __syncthreads();
        for (int ks = 0; ks < 2; ks++) {
            int co = ks * 32 + quad * 8;
            short8 ah0 = *((const short8*)&xh[(mrow0 + l15) * 72 + co]);
            short8 ah1 = *((const short8*)&xh[(mrow0 + 16 + l15) * 72 + co]);
            short8 al0 = *((const short8*)&xl[(mrow0 + l15) * 72 + co]);
            short8 al1 = *((const short8*)&xl[(mrow0 + 16 + l15) * 72 + co]);
            short8 bh0 = *((const short8*)&wh[(ncol0 + l15) * 72 + co]);
            short8 bh1 = *((const short8*)&wh[(ncol0 + 16 + l15) * 72 + co]);
            short8 bl0 = *((const short8*)&wl[(ncol0 + l15) * 72 + co]);
            short8 bl1 = *((const short8*)&wl[(ncol0 + 16 + l15) * 72 + co]);
            acc[0][0] = __builtin_amdgcn_mfma_f32_16x16x32_bf16(ah0, bh0, acc[0][0], 0, 0, 0);
            acc[0][1] = __builtin_amdgcn_mfma_f32_16x16x32_bf16(ah0, bh1, acc[0][1], 0, 0, 0);
            acc[1][0] = __builtin_amdgcn_mfma_f32_16x16x32_bf16(ah1, bh0, acc[1][0], 0, 0, 0);
            acc[1][1] = __builtin_amdgcn_mfma_f32_16x16x32_bf16(ah1, bh1, acc[1][1], 0, 0, 0);
            acc[0][0] = __builtin_amdgcn_mfma_f32_16x16x32_bf16(ah0, bl0, acc[0][0], 0, 0, 0);
            acc[0][1] = __builtin_amdgcn_mfma_f32_16x16x32_bf16(ah0, bl1, acc[0][1], 0, 0, 0);
            acc[1][0] = __builtin_amdgcn_mfma_f32_16x16x32_bf16(ah1, bl0, acc[1][0], 0, 0, 0);
            acc[1][1] = __builtin_amdgcn_mfma_f32_16x16x32_bf16(ah1, bl1, acc[1][1], 0, 0, 0);
            acc[0][0] = __builtin_amdgcn_mfma_f32_16x16x32_bf16(al0, bh0, acc[0][0], 0, 0, 0);
            acc[0][1] = __builtin_amdgcn_mfma_f32_16x16x32_bf16(al0, bh1, acc[0][1], 0, 0, 0);
            acc[1][0] = __builtin_amdgcn_mfma_f32_16x16x32_bf16(al1, bh0, acc[1][0], 0, 0, 0);
            acc[1][1] = __builtin_amdgcn_mfma_f32_16x16x32_bf16(al1, bh1, acc[1][1], 0, 0, 0);
        }
        __syncthreads();
    }
    for (int i = 0; i < 2; i++)
        for (int j = 0; j < 2; j++)
            for (int r = 0; r < 4; r++) {
                int gr = m0 + mrow0 + i * 16 + quad * 4 + r;
                int gc = t0 + ncol0 + j * 16 + l15;
                if (gr < N_TOK) zbuf[(size_t)gr * MID + gc] = acc[i][j][r];
            }
}

// ---------------- z + b -> l2norm -> zn (in place) + zn_h -------------------
__global__ void k_znorm(float* __restrict__ zbuf, const float* __restrict__ b_down,
                        unsigned short* __restrict__ zn_h) {
    int n = blockIdx.x, t = threadIdx.x;
    float v = zbuf[(size_t)n * MID + t] + b_down[t];
    __shared__ float sb[256];
    sb[t] = v * v; __syncthreads();
    for (int s = 128; s > 0; s >>= 1) { if (t < s) sb[t] += sb[t + s]; __syncthreads(); }
    float nn = sqrtf(sb[0]);
    float o = v / fmaxf(nn, EPS_N);
    zbuf[(size_t)n * MID + t] = o;
    zn_h[(size_t)n * MID + t] = f2bf(o);
}

// ---------------- d-GEMM, 128x128 tile, gload_lds mainloop ------------------
// PASS 1: reg epilogue -> part4 per-64-col-half stats (tiny writes)
// PASS 2: LDS-staged fp32 d-tile (stride 132) -> float4-coalesced probs store
//         + ce col-sums + candidate collection in one sweep (round-0 scheme).
template<int PASS>
__global__ __launch_bounds__(256) void k_dpass(const unsigned short* __restrict__ zn_h,
                                               const unsigned short* __restrict__ en_h,
                                               float4* __restrict__ part4,
                                               const float* __restrict__ rs_m,
                                               const float* __restrict__ rs_ist,
                                               const float* __restrict__ rs_is1,
                                               float* __restrict__ ap_acc,
                                               float* __restrict__ out1,
                                               int* __restrict__ ccnt,
                                               int* __restrict__ cand) {
    __shared__ __align__(16) char lds[34048];   // operands 32KB; PASS2 sd 64x132 f32
    int tid = threadIdx.x;
    // XCD-bijective swizzle, kt-major
    int flat = blockIdx.x * NMT128 + blockIdx.y;
    const int NW = NKT128 * NMT128;                  // 3990
    const int q = NW >> 3, r8 = NW & 7;              // 498, 6
    int xcd = flat & 7, sidx = flat >> 3;
    int wg = (xcd < r8 ? xcd * (q + 1) : r8 * (q + 1) + (xcd - r8) * q) + sidx;
    int kt = wg / NMT128, mt = wg - kt * NMT128;
    int m0 = mt * 128, k0 = kt * 128;
    int lane = tid & 63, wv = tid >> 6;
    int quad = lane >> 4, l15 = lane & 15;
    int wr = wv >> 1, wc = wv & 1;          // wave sub-tile: rows wr*64, cols wc*64
    f32x4 acc[4][4] = {};

    int sr = tid >> 3;                      // staging row within 32-row group
    int scb = (tid & 7) * 16;               // dest col byte (0..112)

    for (int step = 0; step < 4; step++) {
        int cB = step * 128;                // global byte offset within row
        #pragma unroll
        for (int it = 0; it < 4; it++) {
            int r = it * 32 + sr;
            int srcb = scb ^ ((r & 7) << 4);     // pre-swizzled source column
            gload16((const char*)zn_h + (size_t)(m0 + r) * 512 + cB + srcb,
                    lds + it * 4096 + wv * 1024);
            gload16((const char*)en_h + (size_t)(k0 + r) * 512 + cB + srcb,
                    lds + 16384 + it * 4096 + wv * 1024);
        }
        __syncthreads();
        #pragma unroll
        for (int ks = 0; ks < 2; ks++) {
            short8 a[4], b[4];
            #pragma unroll
            for (int i = 0; i < 4; i++) {
                int ra = wr * 64 + i * 16 + l15;
                int ca = (ks * 64 + quad * 16) ^ ((ra & 7) << 4);
                a[i] = *(const short8*)(lds + ra * 128 + ca);
                int rb = wc * 64 + i * 16 + l15;
                int cb2 = (ks * 64 + quad * 16) ^ ((rb & 7) << 4);
                b[i] = *(const short8*)(lds + 16384 + rb * 128 + cb2);
            }
            #pragma unroll
            for (int i = 0; i < 4; i++)
                #pragma unroll
                for (int j = 0; j < 4; j++)
                    acc[i][j] = __builtin_amdgcn_mfma_f32_16x16x32_bf16(a[i], b[j], acc[i][j], 0, 0, 0);
        }
        __syncthreads();
    }

    if (PASS == 1) {
        // reg epilogue: per-(row, 64-col half) {min, st, s1, s2} -> part4
        int kth = kt * 2 + wc;              // 64-col half index, 0..139
        #pragma unroll
        for (int i = 0; i < 4; i++) {
            #pragma unroll
            for (int r = 0; r < 4; r++) {
                float dv[4]; float vmin = 1e30f;
                #pragma unroll
                for (int j = 0; j < 4; j++) {
                    int gc = k0 + wc * 64 + j * 16 + l15;
                    float d = 2.f - 2.f * acc[i][j][r];
                    dv[j] = (gc < K_CODE) ? d : 1e30f;
                    vmin = fminf(vmin, dv[j]);
                }
                vmin = fminf(vmin, __shfl_xor(vmin, 1));
                vmin = fminf(vmin, __shfl_xor(vmin, 2));
                vmin = fminf(vmin, __shfl_xor(vmin, 4));
                vmin = fminf(vmin, __shfl_xor(vmin, 8));
                float st = 0.f, s1 = 0.f, s2 = 0.f;
                #pragma unroll
                for (int j = 0; j < 4; j++) {
                    float dd = vmin - dv[j];         // <=0; masked: -1e30 -> exp=0
                    st += __expf(dd * INV_TEMP);
                    float te = dd * INV_ETEMP;
                    float e = __expf(te);
                    s1 += e; s2 += e * te;
                }
                st += __shfl_xor(st, 1); st += __shfl_xor(st, 2);
                st += __shfl_xor(st, 4); st += __shfl_xor(st, 8);
                s1 += __shfl_xor(s1, 1); s1 += __shfl_xor(s1, 2);
                s1 += __shfl_xor(s1, 4); s1 += __shfl_xor(s1, 8);
                s2 += __shfl_xor(s2, 1); s2 += __shfl_xor(s2, 2);
                s2 += __shfl_xor(s2, 4); s2 += __shfl_xor(s2, 8);
                if (l15 == 0) {
                    int gr = m0 + wr * 64 + i * 16 + quad * 4 + r;
                    if (gr < N_TOK) part4[(size_t)gr * N_KT + kth] = make_float4(vmin, st, s1, s2);
                }
            }
        }
    } else {
        // LDS-staged epilogue: two 64-row halves through sd[64][132] f32
        __shared__ float lm[128], lt_[128], l1_[128];
        __shared__ float colacc[8 * 128];
        float* sd = (float*)lds;
        if (tid < 128) {
            int gr = m0 + tid;
            bool ok = gr < N_TOK;
            lm[tid]  = ok ? rs_m[gr]   : 0.f;
            lt_[tid] = ok ? rs_ist[gr] : 0.f;
            l1_[tid] = ok ? rs_is1[gr] : 0.f;
        }
        int g8 = tid >> 5;                  // 0..7 row group
        int c4 = (tid & 31) * 4;            // col 0..124
        int gc = k0 + c4;
        bool okc = gc < K_CODE;             // K_CODE%4==0: float4 fully in or out
        float ce0 = 0.f, ce1 = 0.f, ce2 = 0.f, ce3 = 0.f;
        for (int half = 0; half < 2; half++) {
            if (wr == half) {
                #pragma unroll
                for (int i = 0; i < 4; i++)
                    #pragma unroll
                    for (int j = 0; j < 4; j++)
                        #pragma unroll
                        for (int r = 0; r < 4; r++)
                            sd[(i * 16 + quad * 4 + r) * 132 + wc * 64 + j * 16 + l15] =
                                2.f - 2.f * acc[i][j][r];
            }
            __syncthreads();
            if (okc) {
                #pragma unroll
                for (int rr = 0; rr < 8; rr++) {
                    int lr = rr * 8 + g8;
                    int gr = m0 + half * 64 + lr;
                    if (gr < N_TOK) {
                        float4 d = *(const float4*)(sd + lr * 132 + c4);
                        int sl = half * 64 + lr;
                        float m_ = lm[sl], tt = lt_[sl], i1 = l1_[sl];
                        float thr = m_ + MARGIN;
                        ce0 += __expf((m_ - d.x) * INV_ETEMP) * i1;
                        ce1 += __expf((m_ - d.y) * INV_ETEMP) * i1;
                        ce2 += __expf((m_ - d.z) * INV_ETEMP) * i1;
                        ce3 += __expf((m_ - d.w) * INV_ETEMP) * i1;
                        float4 p;
                        p.x = __expf((m_ - d.x) * INV_TEMP) * tt;
                        p.y = __expf((m_ - d.y) * INV_TEMP) * tt;
                        p.z = __expf((m_ - d.z) * INV_TEMP) * tt;
                        p.w = __expf((m_ - d.w) * INV_TEMP) * tt;
                        *((float4*)(out1 + (size_t)gr * K_CODE + gc)) = p;
                        if (d.x <= thr) { int pd = atomicAdd(&ccnt[gr], 1); if (pd < CAND_CAP) cand[gr * CAND_CAP + pd] = gc + 0; }
                        if (d.y <= thr) { int pd = atomicAdd(&ccnt[gr], 1); if (pd < CAND_CAP) cand[gr * CAND_CAP + pd] = gc + 1; }
                        if (d.z <= thr) { int pd = atomicAdd(&ccnt[gr], 1); if (pd < CAND_CAP) cand[gr * CAND_CAP + pd] = gc + 2; }
                        if (d.w <= thr) { int pd = atomicAdd(&ccnt[gr], 1); if (pd < CAND_CAP) cand[gr * CAND_CAP + pd] = gc + 3; }
                    }
                }
            }
            __syncthreads();                // before next half overwrites sd
        }
        colacc[g8 * 128 + c4 + 0] = ce0;
        colacc[g8 * 128 + c4 + 1] = ce1;
        colacc[g8 * 128 + c4 + 2] = ce2;
        colacc[g8 * 128 + c4 + 3] = ce3;
        __syncthreads();
        if (tid < 128) {
            float s = 0.f;
            #pragma unroll
            for (int g = 0; g < 8; g++) s += colacc[g * 128 + tid];
            int c = k0 + tid;
            if (c < K_CODE) atomicAdd(&ap_acc[c], s);
        }
    }
}

// ---------------- combine 140 tile-partials per row -------------------------
__global__ void k_combine(const float4* __restrict__ part4,
                          float* __restrict__ rs_m, float* __restrict__ rs_ist,
                          float* __restrict__ rs_is1,
                          float* __restrict__ acc4) {
    int sub = threadIdx.x >> 6;
    int row = blockIdx.x * 4 + sub;
    int l = threadIdx.x & 63;
    float4 pv[3];
    float m = 1e30f;
    #pragma unroll
    for (int c = 0; c < 3; c++) {
        int t = l + c * 64;
        pv[c] = (t < N_KT) ? part4[(size_t)row * N_KT + t] : make_float4(1e30f, 0.f, 0.f, 0.f);
        m = fminf(m, pv[c].x);
    }
    #pragma unroll
    for (int s = 1; s < 64; s <<= 1) m = fminf(m, __shfl_xor(m, s));
    float st = 0.f, s1 = 0.f, s2 = 0.f;
    #pragma unroll
    for (int c = 0; c < 3; c++) {
        float mb = pv[c].x;
        int t = l + c * 64;
        if (t < N_KT && mb < 1e29f) {
            float dT = (m - mb) * INV_TEMP;
            st += __expf(dT) * pv[c].y;
            float dE = (m - mb) * INV_ETEMP;
            float e = __expf(dE);
            s1 += e * pv[c].z;
            s2 += e * (pv[c].w + dE * pv[c].z);
        }
    }
    #pragma unroll
    for (int s = 1; s < 64; s <<= 1) {
        st += __shfl_xor(st, s);
        s1 += __shfl_xor(s1, s);
        s2 += __shfl_xor(s2, s);
    }
    if (l == 0) {
        rs_m[row] = m;
        rs_ist[row] = 1.f / st;
        rs_is1[row] = 1.f / s1;
        atomicAdd(&acc4[1], s2 / s1 - __logf(s1));
    }
}

// ---------------- exact fp32 argmin over candidates + out0 fused ------------
__global__ void k_refine(const float* __restrict__ zn, const float* __restrict__ en,
                         const int* __restrict__ ccnt, const int* __restrict__ cand,
                         int* __restrict__ idxb, int* __restrict__ used,
                         float* __restrict__ acc4, float* __restrict__ out0) {
    int n = blockIdx.x * 4 + (threadIdx.x >> 6);
    int lane = threadIdx.x & 63;
    if (n >= N_TOK) return;
    int cnt = ccnt[n];
    if (cnt > CAND_CAP) cnt = CAND_CAP;
    float4 a = ((const float4*)(zn + (size_t)n * MID))[lane];
    float best = 1e30f; int bj = K_CODE;
    for (int c = 0; c < cnt; c++) {
        int code = cand[n * CAND_CAP + c];
        float4 b = ((const float4*)(en + (size_t)code * MID))[lane];
        float s = a.x * b.x + a.y * b.y + a.z * b.z + a.w * b.w;
        #pragma unroll
        for (int off = 1; off < 64; off <<= 1) s += __shfl_xor(s, off);
        float dist = 2.f - 2.f * s;
        if (dist < best || (dist == best && code < bj)) { best = dist; bj = code; }
    }
    float4 b = ((const float4*)(en + (size_t)bj * MID))[lane];
    ((float4*)(out0 + (size_t)n * MID))[lane] = b;      // z_q_ste row = en[bj]
    float dx = b.x - a.x, dy = b.y - a.y, dz = b.z - a.z, dw = b.w - a.w;
    float sq = dx * dx + dy * dy + dz * dz + dw * dw;
    #pragma unroll
    for (int off = 32; off > 0; off >>= 1) sq += __shfl_down(sq, off);
    if (lane == 0) {
        idxb[n] = bj;
        used[bj] = 1;
        atomicAdd(&acc4[0], sq);
    }
}

// ---------------- final scalars ---------------------------------------------
__global__ void k_scal(const int* __restrict__ used, const float* __restrict__ ap_acc,
                       const float* __restrict__ acc4, float* __restrict__ outs) {
    int t = threadIdx.x;
    float uSum = 0.f, aeSum = 0.f;
    for (int k = t; k < K_CODE; k += 256) {
        uSum += (float)used[k];
        float ap = ap_acc[k] * (1.0f / (float)N_TOK);
        aeSum += ap * __logf(ap + 1e-5f);
    }
    __shared__ float sb[256];
    sb[t] = uSum; __syncthreads();
    for (int s = 128; s > 0; s >>= 1) { if (t < s) sb[t] += sb[t + s]; __syncthreads(); }
    uSum = sb[0];
    __syncthreads(); sb[t] = aeSum; __syncthreads();
    for (int s = 128; s > 0; s >>= 1) { if (t < s) sb[t] += sb[t + s]; __syncthreads(); }
    aeSum = sb[0];
    if (t == 0) {
        outs[0] = uSum / (float)K_CODE;
        float vq = acc4[0] / (float)((size_t)N_TOK * MID);
        outs[1] = vq;
        outs[2] = vq;
        outs[3] = -(acc4[1] / (float)N_TOK) + aeSum;
    }
}

extern "C" void kernel_launch(void* const* d_in, const int* in_sizes, int n_in,
                              void* d_out, int out_size, void* d_ws, size_t ws_size,
                              hipStream_t stream) {
    const float* x   = (const float*)d_in[0];
    const float* W   = (const float*)d_in[1];
    const float* b   = (const float*)d_in[2];
    const float* emb = (const float*)d_in[3];

    float* out  = (float*)d_out;
    float* out0 = out;                                                  // [7200*256]
    float* out1 = out + (size_t)N_TOK * MID;                            // probs
    float* outs = out + (size_t)N_TOK * MID + (size_t)N_TOK * K_CODE;   // 4 scalars

    char* w = (char*)d_ws;
    size_t off = 0;
    auto carve = [&](size_t bytes) { void* p = w + off; off += (bytes + 255) & ~(size_t)255; return p; };
    float*          zn    = (float*)         carve((size_t)N_PAD * MID * 4);
    float*          en    = (float*)         carve((size_t)K_PAD * MID * 4);
    unsigned short* zn_h  = (unsigned short*)carve((size_t)N_PAD_A * MID * 2);
    unsigned short* en_h  = (unsigned short*)carve((size_t)K_PAD * MID * 2);
    unsigned short* wt_h  = (unsigned short*)carve((size_t)MID * C_DIM * 2);
    unsigned short* wt_l  = (unsigned short*)carve((size_t)MID * C_DIM * 2);
    float4*         part4 = (float4*)        carve((size_t)N_TOK * N_KT * 16);
    float*          rs_m  = (float*)         carve((size_t)N_TOK * 4);
    float*          rs_ist= (float*)         carve((size_t)N_TOK * 4);
    float*          rs_is1= (float*)         carve((size_t)N_TOK * 4);
    int*            ccnt  = (int*)           carve((size_t)N_TOK * 4);
    int*            cand  = (int*)           carve((size_t)N_TOK * CAND_CAP * 4);
    int*            idxb  = (int*)           carve((size_t)N_TOK * 4);
    float*          ap_acc= (float*)         carve((size_t)K_CODE * 4);
    int*            used  = (int*)           carve((size_t)K_CODE * 4);
    float*          acc4  = (float*)         carve(16);
    (void)ws_size; (void)in_sizes; (void)n_in; (void)out_size;

    k_prep   <<<K_CODE + 768 + 35, 256, 0, stream>>>(emb, en, en_h, W, wt_h, wt_l,
                                                     ap_acc, used, acc4, ccnt, zn_h);
    k_zgemm  <<<dim3(4, 113), 256, 0, stream>>>(x, wt_h, wt_l, zn);
    k_znorm  <<<N_TOK, 256, 0, stream>>>(zn, b, zn_h);
    k_dpass<1><<<dim3(NKT128, NMT128), 256, 0, stream>>>(zn_h, en_h, part4, rs_m, rs_ist, rs_is1, ap_acc, out1, ccnt, cand);
    k_combine<<<N_TOK / 4, 256, 0, stream>>>(part4, rs_m, rs_ist, rs_is1, acc4);
    k_dpass<2><<<dim3(NKT128, NMT128), 256, 0, stream>>>(zn_h, en_h, part4, rs_m, rs_ist, rs_is1, ap_acc, out1, ccnt, cand);
    k_refine <<<N_TOK / 4, 256, 0, stream>>>(zn, en, ccnt, cand, idxb, used, acc4, out0);
    k_scal   <<<1, 256, 0, stream>>>(used, ap_acc, acc4, outs);
}

// Round 5
// 644.141 us; speedup vs baseline: 1.1135x; 1.0781x over previous
//
#include <hip/hip_runtime.h>
#include <stdint.h>

#define N_TOK 7200
#define N_PAD 7232      // 113*64
#define K_CODE 8912
#define K_PAD 8960      // 140*64
#define N_KT 140
#define MID 256
#define C_DIM 768
#define INV_TEMP (1.0f/0.07f)
#define INV_ETEMP 100.0f
#define MARGIN 0.02f
#define CAND_CAP 64
#define EPS_N 1e-12f

typedef __attribute__((ext_vector_type(8))) short short8;   // 8 bf16 (4 VGPRs)
typedef __attribute__((ext_vector_type(4))) float f32x4;

__device__ __forceinline__ unsigned short f2bf(float f) {
    unsigned u = __float_as_uint(f);
    u += 0x7fffu + ((u >> 16) & 1u);   // round-to-nearest-even
    return (unsigned short)(u >> 16);
}
__device__ __forceinline__ float bf2f(unsigned short h) {
    return __uint_as_float(((unsigned)h) << 16);
}

// ---------------- fused prep: ennorm | wsplit | xsplit | init ---------------
// blocks [0,K_CODE)                 : embedding l2norm -> en (f32) + en_h (bf16)
// blocks [K_CODE, +768)             : W_down -> transposed bf16 hi/lo splits
// blocks [K_CODE+768, +5400)        : x -> bf16 hi/lo splits (row-major)
// blocks [K_CODE+768+5400, +35)     : zero accumulators
__global__ void k_prep(const float* __restrict__ emb,
                       float* __restrict__ en, unsigned short* __restrict__ en_h,
                       const float* __restrict__ W,
                       unsigned short* __restrict__ wt_h, unsigned short* __restrict__ wt_l,
                       const float* __restrict__ x,
                       unsigned short* __restrict__ xh_g, unsigned short* __restrict__ xl_g,
                       float* __restrict__ ap_acc, int* __restrict__ used,
                       float* __restrict__ acc4, int* __restrict__ ccnt) {
    __shared__ float sb[256];
    int b = blockIdx.x, t = threadIdx.x;
    if (b < K_CODE) {
        float v = emb[b * MID + t];
        sb[t] = v * v; __syncthreads();
        for (int s = 128; s > 0; s >>= 1) { if (t < s) sb[t] += sb[t + s]; __syncthreads(); }
        float nn = sqrtf(sb[0]);
        float o = v / fmaxf(nn, EPS_N);
        en[b * MID + t] = o;
        en_h[b * MID + t] = f2bf(o);
    } else if (b < K_CODE + 768) {
        int i = (b - K_CODE) * 256 + t;       // < C_DIM*MID exactly
        int c = i / MID, tc = i % MID;
        float v = W[i];
        unsigned short h = f2bf(v);
        unsigned short l = f2bf(v - bf2f(h));
        wt_h[tc * C_DIM + c] = h;
        wt_l[tc * C_DIM + c] = l;
    } else if (b < K_CODE + 768 + 5400) {
        // 5400*256*4 == 7200*768 exactly
        size_t i4 = ((size_t)(b - K_CODE - 768) * 256 + t) * 4;
        float4 v = *(const float4*)(x + i4);
        unsigned short h0 = f2bf(v.x), h1 = f2bf(v.y), h2 = f2bf(v.z), h3 = f2bf(v.w);
        *((ushort4*)(xh_g + i4)) = make_ushort4(h0, h1, h2, h3);
        *((ushort4*)(xl_g + i4)) = make_ushort4(f2bf(v.x - bf2f(h0)), f2bf(v.y - bf2f(h1)),
                                                f2bf(v.z - bf2f(h2)), f2bf(v.w - bf2f(h3)));
    } else {
        int i = (b - K_CODE - 768 - 5400) * 256 + t;
        if (i < K_CODE) { ap_acc[i] = 0.f; used[i] = 0; }
        if (i < N_TOK) ccnt[i] = 0;
        if (i < 4) acc4[i] = 0.f;
    }
}

// ---------------- z = x @ W_down via bf16x3 MFMA (fp32-quality) -------------
__global__ __launch_bounds__(256) void k_zgemm(const unsigned short* __restrict__ xh_g,
                                               const unsigned short* __restrict__ xl_g,
                                               const unsigned short* __restrict__ wt_h,
                                               const unsigned short* __restrict__ wt_l,
                                               float* __restrict__ zbuf) {
    __shared__ unsigned short ls[4 * 64 * 72];
    unsigned short* xh = ls;
    unsigned short* xl = ls + 64 * 72;
    unsigned short* wh = ls + 2 * 64 * 72;
    unsigned short* wl = ls + 3 * 64 * 72;
    int tid = threadIdx.x;
    int m0 = blockIdx.y * 64;
    int t0 = blockIdx.x * 64;
    int lane = tid & 63, wv = tid >> 6;
    int quad = lane >> 4, l15 = lane & 15;
    int mrow0 = (wv >> 1) * 32, ncol0 = (wv & 1) * 32;
    f32x4 acc[2][2] = {};

    for (int ch = 0; ch < 12; ch++) {
        int c0 = ch * 64;
        for (int it = 0; it < 2; it++) {
            int r = it * 32 + (tid >> 3);
            int cq = tid & 7;
            int gr = m0 + r;
            uint4 vh = make_uint4(0, 0, 0, 0), vl = make_uint4(0, 0, 0, 0);
            if (gr < N_TOK) {
                vh = ((const uint4*)xh_g)[(size_t)gr * (C_DIM / 8) + (c0 >> 3) + cq];
                vl = ((const uint4*)xl_g)[(size_t)gr * (C_DIM / 8) + (c0 >> 3) + cq];
            }
            *((uint4*)&xh[r * 72 + cq * 8]) = vh;
            *((uint4*)&xl[r * 72 + cq * 8]) = vl;
        }
        for (int it = 0; it < 2; it++) {
            int r = it * 32 + (tid >> 3);
            int cq = tid & 7;
            uint4 vh = ((const uint4*)wt_h)[(size_t)(t0 + r) * (C_DIM / 8) + (c0 >> 3) + cq];
            uint4 vl = ((const uint4*)wt_l)[(size_t)(t0 + r) * (C_DIM / 8) + (c0 >> 3) + cq];
            *((uint4*)&wh[r * 72 + cq * 8]) = vh;
            *((uint4*)&wl[r * 72 + cq * 8]) = vl;
        }
        __syncthreads();
        for (int ks = 0; ks < 2; ks++) {
            int co = ks * 32 + quad * 8;
            short8 ah0 = *((const short8*)&xh[(mrow0 + l15) * 72 + co]);
            short8 ah1 = *((const short8*)&xh[(mrow0 + 16 + l15) * 72 + co]);
            short8 al0 = *((const short8*)&xl[(mrow0 + l15) * 72 + co]);
            short8 al1 = *((const short8*)&xl[(mrow0 + 16 + l15) * 72 + co]);
            short8 bh0 = *((const short8*)&wh[(ncol0 + l15) * 72 + co]);
            short8 bh1 = *((const short8*)&wh[(ncol0 + 16 + l15) * 72 + co]);
            short8 bl0 = *((const short8*)&wl[(ncol0 + l15) * 72 + co]);
            short8 bl1 = *((const short8*)&wl[(ncol0 + 16 + l15) * 72 + co]);
            acc[0][0] = __builtin_amdgcn_mfma_f32_16x16x32_bf16(ah0, bh0, acc[0][0], 0, 0, 0);
            acc[0][1] = __builtin_amdgcn_mfma_f32_16x16x32_bf16(ah0, bh1, acc[0][1], 0, 0, 0);
            acc[1][0] = __builtin_amdgcn_mfma_f32_16x16x32_bf16(ah1, bh0, acc[1][0], 0, 0, 0);
            acc[1][1] = __builtin_amdgcn_mfma_f32_16x16x32_bf16(ah1, bh1, acc[1][1], 0, 0, 0);
            acc[0][0] = __builtin_amdgcn_mfma_f32_16x16x32_bf16(ah0, bl0, acc[0][0], 0, 0, 0);
            acc[0][1] = __builtin_amdgcn_mfma_f32_16x16x32_bf16(ah0, bl1, acc[0][1], 0, 0, 0);
            acc[1][0] = __builtin_amdgcn_mfma_f32_16x16x32_bf16(ah1, bl0, acc[1][0], 0, 0, 0);
            acc[1][1] = __builtin_amdgcn_mfma_f32_16x16x32_bf16(ah1, bl1, acc[1][1], 0, 0, 0);
            acc[0][0] = __builtin_amdgcn_mfma_f32_16x16x32_bf16(al0, bh0, acc[0][0], 0, 0, 0);
            acc[0][1] = __builtin_amdgcn_mfma_f32_16x16x32_bf16(al0, bh1, acc[0][1], 0, 0, 0);
            acc[1][0] = __builtin_amdgcn_mfma_f32_16x16x32_bf16(al1, bh0, acc[1][0], 0, 0, 0);
            acc[1][1] = __builtin_amdgcn_mfma_f32_16x16x32_bf16(al1, bh1, acc[1][1], 0, 0, 0);
        }
        __syncthreads();
    }
    for (int i = 0; i < 2; i++)
        for (int j = 0; j < 2; j++)
            for (int r = 0; r < 4; r++) {
                int gr = m0 + mrow0 + i * 16 + quad * 4 + r;
                int gc = t0 + ncol0 + j * 16 + l15;
                if (gr < N_TOK) zbuf[(size_t)gr * MID + gc] = acc[i][j][r];
            }
}

// ---------------- z + b -> l2norm -> zn (in place) + zn_h -------------------
__global__ void k_znorm(float* __restrict__ zbuf, const float* __restrict__ b_down,
                        unsigned short* __restrict__ zn_h) {
    int n = blockIdx.x, t = threadIdx.x;
    float v = zbuf[(size_t)n * MID + t] + b_down[t];
    __shared__ float sb[256];
    sb[t] = v * v; __syncthreads();
    for (int s = 128; s > 0; s >>= 1) { if (t < s) sb[t] += sb[t + s]; __syncthreads(); }
    float nn = sqrtf(sb[0]);
    float o = v / fmaxf(nn, EPS_N);
    zbuf[(size_t)n * MID + t] = o;
    zn_h[(size_t)n * MID + t] = f2bf(o);
}

// ---------------- d-GEMM, two passes, no d materialization ------------------
// PASS 1: per-(row, col-tile) partials {min, st, s1, s2} -> part4
// PASS 2: probs -> out1, avg_probs column sums, element-level candidates
template<int PASS>
__global__ __launch_bounds__(256) void k_dpass(const unsigned short* __restrict__ zn_h,
                                               const unsigned short* __restrict__ en_h,
                                               float4* __restrict__ part4,
                                               const float* __restrict__ rs_m,
                                               const float* __restrict__ rs_ist,
                                               const float* __restrict__ rs_is1,
                                               float* __restrict__ ap_acc,
                                               float* __restrict__ out1,
                                               int* __restrict__ ccnt,
                                               int* __restrict__ cand) {
    __shared__ __align__(16) char smem[2 * 64 * 136 * 2];
    unsigned short* at = (unsigned short*)smem;
    unsigned short* bt = at + 64 * 136;
    int tid = threadIdx.x;
    int kt = blockIdx.x, mt = blockIdx.y;
    int m0 = mt * 64, k0c = kt * 64;
    int lane = tid & 63, wv = tid >> 6;
    int quad = lane >> 4, l15 = lane & 15;
    int mrow0 = (wv >> 1) * 32, ncol0 = (wv & 1) * 32;
    f32x4 acc[2][2] = {};

    for (int ch = 0; ch < 2; ch++) {
        int c0 = ch * 128;
        for (int it = 0; it < 4; it++) {
            int r = it * 16 + (tid >> 4);
            int cq = tid & 15;
            uint4 va = ((const uint4*)zn_h)[(size_t)(m0 + r) * (MID / 8) + (c0 >> 3) + cq];
            uint4 vb = ((const uint4*)en_h)[(size_t)(k0c + r) * (MID / 8) + (c0 >> 3) + cq];
            *((uint4*)&at[r * 136 + cq * 8]) = va;
            *((uint4*)&bt[r * 136 + cq * 8]) = vb;
        }
        __syncthreads();
        for (int ks = 0; ks < 4; ks++) {
            int co = ks * 32 + quad * 8;
            short8 a0 = *((const short8*)&at[(mrow0 + l15) * 136 + co]);
            short8 a1 = *((const short8*)&at[(mrow0 + 16 + l15) * 136 + co]);
            short8 b0 = *((const short8*)&bt[(ncol0 + l15) * 136 + co]);
            short8 b1 = *((const short8*)&bt[(ncol0 + 16 + l15) * 136 + co]);
            acc[0][0] = __builtin_amdgcn_mfma_f32_16x16x32_bf16(a0, b0, acc[0][0], 0, 0, 0);
            acc[0][1] = __builtin_amdgcn_mfma_f32_16x16x32_bf16(a0, b1, acc[0][1], 0, 0, 0);
            acc[1][0] = __builtin_amdgcn_mfma_f32_16x16x32_bf16(a1, b0, acc[1][0], 0, 0, 0);
            acc[1][1] = __builtin_amdgcn_mfma_f32_16x16x32_bf16(a1, b1, acc[1][1], 0, 0, 0);
        }
        __syncthreads();
    }

    // ---- epilogue: reuse smem as fp32 d-tile [64][68] + small arrays ----
    float* sd = (float*)smem;                  // 64*68*4 = 17408 B
    float* lm = sd + 64 * 68;                  // 64
    float* lt = lm + 64;                       // 64
    float* l1 = lt + 64;                       // 64
    float* colacc = l1 + 64;                   // 256

    if (PASS == 2) {
        if (tid < 64) {
            int gr = m0 + tid;
            bool okr = gr < N_TOK;
            lm[tid] = okr ? rs_m[gr] : 0.f;
            lt[tid] = okr ? rs_ist[gr] : 0.f;
            l1[tid] = okr ? rs_is1[gr] : 0.f;
        }
    }
    for (int i = 0; i < 2; i++)
        for (int j = 0; j < 2; j++)
            for (int r = 0; r < 4; r++) {
                int lr = mrow0 + i * 16 + quad * 4 + r;
                int lc = ncol0 + j * 16 + l15;
                int gc = k0c + lc;
                float dv = (gc < K_CODE) ? (2.f - 2.f * acc[i][j][r]) : 1e30f;
                sd[lr * 68 + lc] = dv;
            }
    __syncthreads();

    if (PASS == 1) {
        // 4 waves x 16 rows, 4 lanes/row, 16 values/lane
        int rloc = wv * 16 + (lane >> 2);
        const float* rowp = sd + rloc * 68 + (lane & 3) * 16;
        float vals[16];
        float vmin = 1e30f;
        #pragma unroll
        for (int i = 0; i < 16; i++) { vals[i] = rowp[i]; vmin = fminf(vmin, vals[i]); }
        vmin = fminf(vmin, __shfl_xor(vmin, 1));
        vmin = fminf(vmin, __shfl_xor(vmin, 2));
        float st = 0.f, s1 = 0.f, s2 = 0.f;
        #pragma unroll
        for (int i = 0; i < 16; i++) {
            float dd = vmin - vals[i];
            st += __expf(dd * INV_TEMP);
            float te = dd * INV_ETEMP;
            float e = __expf(te);
            s1 += e; s2 += e * te;
        }
        st += __shfl_xor(st, 1); st += __shfl_xor(st, 2);
        s1 += __shfl_xor(s1, 1); s1 += __shfl_xor(s1, 2);
        s2 += __shfl_xor(s2, 1); s2 += __shfl_xor(s2, 2);
        if ((lane & 3) == 0) {
            int gr = m0 + rloc;
            if (gr < N_TOK) part4[(size_t)gr * N_KT + kt] = make_float4(vmin, st, s1, s2);
        }
    } else {
        // phase A: avg_probs column sums
        int col = tid & 63, rq = tid >> 6;
        float ce = 0.f;
        #pragma unroll
        for (int r16 = 0; r16 < 16; r16++) {
            int lr = rq * 16 + r16;
            float dv = sd[lr * 68 + col];
            ce += __expf((lm[lr] - dv) * INV_ETEMP) * l1[lr];
        }
        colacc[rq * 64 + col] = ce;
        __syncthreads();
        if (tid < 64) {
            float s = colacc[tid] + colacc[64 + tid] + colacc[128 + tid] + colacc[192 + tid];
            int gc = k0c + tid;
            if (gc < K_CODE) atomicAdd(&ap_acc[gc], s);
        }
        // phase B: probs store (float4) + element-level candidate collection
        #pragma unroll
        for (int it = 0; it < 4; it++) {
            int idx = it * 256 + tid;
            int lr = idx >> 4, c4 = idx & 15;
            int gr = m0 + lr;
            if (gr >= N_TOK) continue;
            int gc = k0c + c4 * 4;
            if (gc >= K_CODE) continue;           // K_CODE % 4 == 0: fully in or out
            float4 v = *((const float4*)(sd + lr * 68 + c4 * 4));
            float mm = lm[lr], tt = lt[lr];
            float thr = mm + MARGIN;
            if (v.x <= thr) { int p = atomicAdd(&ccnt[gr], 1); if (p < CAND_CAP) cand[gr * CAND_CAP + p] = gc + 0; }
            if (v.y <= thr) { int p = atomicAdd(&ccnt[gr], 1); if (p < CAND_CAP) cand[gr * CAND_CAP + p] = gc + 1; }
            if (v.z <= thr) { int p = atomicAdd(&ccnt[gr], 1); if (p < CAND_CAP) cand[gr * CAND_CAP + p] = gc + 2; }
            if (v.w <= thr) { int p = atomicAdd(&ccnt[gr], 1); if (p < CAND_CAP) cand[gr * CAND_CAP + p] = gc + 3; }
            float4 p;
            p.x = __expf((mm - v.x) * INV_TEMP) * tt;
            p.y = __expf((mm - v.y) * INV_TEMP) * tt;
            p.z = __expf((mm - v.z) * INV_TEMP) * tt;
            p.w = __expf((mm - v.w) * INV_TEMP) * tt;
            *((float4*)(out1 + (size_t)gr * K_CODE + gc)) = p;
        }
    }
}

// ---------------- combine 140 tile-partials per row -------------------------
__global__ void k_combine(const float4* __restrict__ part4,
                          float* __restrict__ rs_m, float* __restrict__ rs_ist,
                          float* __restrict__ rs_is1,
                          float* __restrict__ acc4) {
    int sub = threadIdx.x >> 6;
    int row = blockIdx.x * 4 + sub;
    int l = threadIdx.x & 63;
    float4 pv[3];
    float m = 1e30f;
    #pragma unroll
    for (int c = 0; c < 3; c++) {
        int t = l + c * 64;
        pv[c] = (t < N_KT) ? part4[(size_t)row * N_KT + t] : make_float4(1e30f, 0.f, 0.f, 0.f);
        m = fminf(m, pv[c].x);
    }
    #pragma unroll
    for (int s = 1; s < 64; s <<= 1) m = fminf(m, __shfl_xor(m, s));
    float st = 0.f, s1 = 0.f, s2 = 0.f;
    #pragma unroll
    for (int c = 0; c < 3; c++) {
        float mb = pv[c].x;
        int t = l + c * 64;
        if (t < N_KT && mb < 1e29f) {
            float dT = (m - mb) * INV_TEMP;
            st += __expf(dT) * pv[c].y;
            float dE = (m - mb) * INV_ETEMP;
            float e = __expf(dE);
            s1 += e * pv[c].z;
            s2 += e * (pv[c].w + dE * pv[c].z);
        }
    }
    #pragma unroll
    for (int s = 1; s < 64; s <<= 1) {
        st += __shfl_xor(st, s);
        s1 += __shfl_xor(s1, s);
        s2 += __shfl_xor(s2, s);
    }
    if (l == 0) {
        rs_m[row] = m;
        rs_ist[row] = 1.f / st;
        rs_is1[row] = 1.f / s1;
        atomicAdd(&acc4[1], s2 / s1 - __logf(s1));
    }
}

// ---------------- exact fp32 argmin over candidates + out0 fused ------------
__global__ void k_refine(const float* __restrict__ zn, const float* __restrict__ en,
                         const int* __restrict__ ccnt, const int* __restrict__ cand,
                         int* __restrict__ idxb, int* __restrict__ used,
                         float* __restrict__ acc4, float* __restrict__ out0) {
    int n = blockIdx.x * 4 + (threadIdx.x >> 6);
    int lane = threadIdx.x & 63;
    if (n >= N_TOK) return;
    int cnt = ccnt[n];
    if (cnt > CAND_CAP) cnt = CAND_CAP;
    float4 a = ((const float4*)(zn + (size_t)n * MID))[lane];
    float best = 1e30f; int bj = K_CODE;
    for (int c = 0; c < cnt; c++) {
        int code = cand[n * CAND_CAP + c];
        float4 b = ((const float4*)(en + (size_t)code * MID))[lane];
        float s = a.x * b.x + a.y * b.y + a.z * b.z + a.w * b.w;
        #pragma unroll
        for (int off = 1; off < 64; off <<= 1) s += __shfl_xor(s, off);
        float dist = 2.f - 2.f * s;
        if (dist < best || (dist == best && code < bj)) { best = dist; bj = code; }
    }
    float4 b = ((const float4*)(en + (size_t)bj * MID))[lane];
    ((float4*)(out0 + (size_t)n * MID))[lane] = b;      // z_q_ste row = en[bj]
    float dx = b.x - a.x, dy = b.y - a.y, dz = b.z - a.z, dw = b.w - a.w;
    float sq = dx * dx + dy * dy + dz * dz + dw * dw;
    #pragma unroll
    for (int off = 32; off > 0; off >>= 1) sq += __shfl_down(sq, off);
    if (lane == 0) {
        idxb[n] = bj;
        used[bj] = 1;
        atomicAdd(&acc4[0], sq);
    }
}

// ---------------- final scalars ---------------------------------------------
__global__ void k_scal(const int* __restrict__ used, const float* __restrict__ ap_acc,
                       const float* __restrict__ acc4, float* __restrict__ outs) {
    int t = threadIdx.x;
    float uSum = 0.f, aeSum = 0.f;
    for (int k = t; k < K_CODE; k += 256) {
        uSum += (float)used[k];
        float ap = ap_acc[k] * (1.0f / (float)N_TOK);
        aeSum += ap * __logf(ap + 1e-5f);
    }
    __shared__ float sb[256];
    sb[t] = uSum; __syncthreads();
    for (int s = 128; s > 0; s >>= 1) { if (t < s) sb[t] += sb[t + s]; __syncthreads(); }
    uSum = sb[0];
    __syncthreads(); sb[t] = aeSum; __syncthreads();
    for (int s = 128; s > 0; s >>= 1) { if (t < s) sb[t] += sb[t + s]; __syncthreads(); }
    aeSum = sb[0];
    if (t == 0) {
        outs[0] = uSum / (float)K_CODE;
        float vq = acc4[0] / (float)((size_t)N_TOK * MID);
        outs[1] = vq;
        outs[2] = vq;
        outs[3] = -(acc4[1] / (float)N_TOK) + aeSum;
    }
}

extern "C" void kernel_launch(void* const* d_in, const int* in_sizes, int n_in,
                              void* d_out, int out_size, void* d_ws, size_t ws_size,
                              hipStream_t stream) {
    const float* x   = (const float*)d_in[0];
    const float* W   = (const float*)d_in[1];
    const float* b   = (const float*)d_in[2];
    const float* emb = (const float*)d_in[3];

    float* out  = (float*)d_out;
    float* out0 = out;                                                  // [7200*256]
    float* out1 = out + (size_t)N_TOK * MID;                            // probs
    float* outs = out + (size_t)N_TOK * MID + (size_t)N_TOK * K_CODE;   // 4 scalars

    char* w = (char*)d_ws;
    size_t off = 0;
    auto carve = [&](size_t bytes) { void* p = w + off; off += (bytes + 255) & ~(size_t)255; return p; };
    float*          zn    = (float*)         carve((size_t)N_PAD * MID * 4);
    float*          en    = (float*)         carve((size_t)K_PAD * MID * 4);
    unsigned short* zn_h  = (unsigned short*)carve((size_t)N_PAD * MID * 2);
    unsigned short* en_h  = (unsigned short*)carve((size_t)K_PAD * MID * 2);
    unsigned short* wt_h  = (unsigned short*)carve((size_t)MID * C_DIM * 2);
    unsigned short* wt_l  = (unsigned short*)carve((size_t)MID * C_DIM * 2);
    unsigned short* xh_g  = (unsigned short*)carve((size_t)N_TOK * C_DIM * 2);
    unsigned short* xl_g  = (unsigned short*)carve((size_t)N_TOK * C_DIM * 2);
    float4*         part4 = (float4*)        carve((size_t)N_TOK * N_KT * 16);
    float*          rs_m  = (float*)         carve((size_t)N_TOK * 4);
    float*          rs_ist= (float*)         carve((size_t)N_TOK * 4);
    float*          rs_is1= (float*)         carve((size_t)N_TOK * 4);
    int*            ccnt  = (int*)           carve((size_t)N_TOK * 4);
    int*            cand  = (int*)           carve((size_t)N_TOK * CAND_CAP * 4);
    int*            idxb  = (int*)           carve((size_t)N_TOK * 4);
    float*          ap_acc= (float*)         carve((size_t)K_CODE * 4);
    int*            used  = (int*)           carve((size_t)K_CODE * 4);
    float*          acc4  = (float*)         carve(16);
    (void)ws_size; (void)in_sizes; (void)n_in; (void)out_size;

    k_prep   <<<K_CODE + 768 + 5400 + 35, 256, 0, stream>>>(emb, en, en_h, W, wt_h, wt_l,
                                                            x, xh_g, xl_g,
                                                            ap_acc, used, acc4, ccnt);
    k_zgemm  <<<dim3(4, 113), 256, 0, stream>>>(xh_g, xl_g, wt_h, wt_l, zn);
    k_znorm  <<<N_TOK, 256, 0, stream>>>(zn, b, zn_h);
    k_dpass<1><<<dim3(N_KT, 113), 256, 0, stream>>>(zn_h, en_h, part4, rs_m, rs_ist, rs_is1, ap_acc, out1, ccnt, cand);
    k_combine<<<N_TOK / 4, 256, 0, stream>>>(part4, rs_m, rs_ist, rs_is1, acc4);
    k_dpass<2><<<dim3(N_KT, 113), 256, 0, stream>>>(zn_h, en_h, part4, rs_m, rs_ist, rs_is1, ap_acc, out1, ccnt, cand);
    k_refine <<<N_TOK / 4, 256, 0, stream>>>(zn, en, ccnt, cand, idxb, used, acc4, out0);
    k_scal   <<<1, 256, 0, stream>>>(used, ap_acc, acc4, outs);
}

// Round 10
// 643.673 us; speedup vs baseline: 1.1143x; 1.0007x over previous
//
#include <hip/hip_runtime.h>
#include <stdint.h>

#define N_TOK 7200
#define N_PAD 7232      // 113*64
#define K_CODE 8912
#define K_PAD 8960      // 140*64
#define N_KT 140
#define MID 256
#define C_DIM 768
#define INV_TEMP (1.0f/0.07f)
#define INV_ETEMP 100.0f
#define MARGIN 0.02f
#define CAND_CAP 64
#define EPS_N 1e-12f

typedef __attribute__((ext_vector_type(8))) short short8;   // 8 bf16 (4 VGPRs)
typedef __attribute__((ext_vector_type(4))) float f32x4;

__device__ __forceinline__ unsigned short f2bf(float f) {
    unsigned u = __float_as_uint(f);
    u += 0x7fffu + ((u >> 16) & 1u);   // round-to-nearest-even
    return (unsigned short)(u >> 16);
}
__device__ __forceinline__ float bf2f(unsigned short h) {
    return __uint_as_float(((unsigned)h) << 16);
}
// non-temporal f32x4 store (native ext_vector type: accepted by the builtin)
__device__ __forceinline__ void nt_store4(float* p, float a, float b, float c, float d) {
    f32x4 v; v.x = a; v.y = b; v.z = c; v.w = d;
    __builtin_nontemporal_store(v, (f32x4*)p);
}

// ---------------- fused prep: ennorm | wsplit | xsplit | init ---------------
__global__ void k_prep(const float* __restrict__ emb,
                       float* __restrict__ en, unsigned short* __restrict__ en_h,
                       const float* __restrict__ W,
                       unsigned short* __restrict__ wt_h, unsigned short* __restrict__ wt_l,
                       const float* __restrict__ x,
                       unsigned short* __restrict__ xh_g, unsigned short* __restrict__ xl_g,
                       float* __restrict__ ap_acc, int* __restrict__ used,
                       float* __restrict__ acc4, int* __restrict__ ccnt) {
    __shared__ float sb[256];
    int b = blockIdx.x, t = threadIdx.x;
    if (b < K_CODE) {
        float v = emb[b * MID + t];
        sb[t] = v * v; __syncthreads();
        for (int s = 128; s > 0; s >>= 1) { if (t < s) sb[t] += sb[t + s]; __syncthreads(); }
        float nn = sqrtf(sb[0]);
        float o = v / fmaxf(nn, EPS_N);
        en[b * MID + t] = o;
        en_h[b * MID + t] = f2bf(o);
    } else if (b < K_CODE + 768) {
        int i = (b - K_CODE) * 256 + t;       // < C_DIM*MID exactly
        int c = i / MID, tc = i % MID;
        float v = W[i];
        unsigned short h = f2bf(v);
        unsigned short l = f2bf(v - bf2f(h));
        wt_h[tc * C_DIM + c] = h;
        wt_l[tc * C_DIM + c] = l;
    } else if (b < K_CODE + 768 + 5400) {
        // 5400*256*4 == 7200*768 exactly
        size_t i4 = ((size_t)(b - K_CODE - 768) * 256 + t) * 4;
        float4 v = *(const float4*)(x + i4);
        unsigned short h0 = f2bf(v.x), h1 = f2bf(v.y), h2 = f2bf(v.z), h3 = f2bf(v.w);
        *((ushort4*)(xh_g + i4)) = make_ushort4(h0, h1, h2, h3);
        *((ushort4*)(xl_g + i4)) = make_ushort4(f2bf(v.x - bf2f(h0)), f2bf(v.y - bf2f(h1)),
                                                f2bf(v.z - bf2f(h2)), f2bf(v.w - bf2f(h3)));
    } else {
        int i = (b - K_CODE - 768 - 5400) * 256 + t;
        if (i < K_CODE) { ap_acc[i] = 0.f; used[i] = 0; }
        if (i < N_TOK) ccnt[i] = 0;
        if (i < 4) acc4[i] = 0.f;
    }
}

// ---------------- z = x @ W_down via bf16x3 MFMA (fp32-quality) -------------
__global__ __launch_bounds__(256) void k_zgemm(const unsigned short* __restrict__ xh_g,
                                               const unsigned short* __restrict__ xl_g,
                                               const unsigned short* __restrict__ wt_h,
                                               const unsigned short* __restrict__ wt_l,
                                               float* __restrict__ zbuf) {
    __shared__ unsigned short ls[4 * 64 * 72];
    unsigned short* xh = ls;
    unsigned short* xl = ls + 64 * 72;
    unsigned short* wh = ls + 2 * 64 * 72;
    unsigned short* wl = ls + 3 * 64 * 72;
    int tid = threadIdx.x;
    int m0 = blockIdx.y * 64;
    int t0 = blockIdx.x * 64;
    int lane = tid & 63, wv = tid >> 6;
    int quad = lane >> 4, l15 = lane & 15;
    int mrow0 = (wv >> 1) * 32, ncol0 = (wv & 1) * 32;
    f32x4 acc[2][2] = {};

    for (int ch = 0; ch < 12; ch++) {
        int c0 = ch * 64;
        for (int it = 0; it < 2; it++) {
            int r = it * 32 + (tid >> 3);
            int cq = tid & 7;
            int gr = m0 + r;
            uint4 vh = make_uint4(0, 0, 0, 0), vl = make_uint4(0, 0, 0, 0);
            if (gr < N_TOK) {
                vh = ((const uint4*)xh_g)[(size_t)gr * (C_DIM / 8) + (c0 >> 3) + cq];
                vl = ((const uint4*)xl_g)[(size_t)gr * (C_DIM / 8) + (c0 >> 3) + cq];
            }
            *((uint4*)&xh[r * 72 + cq * 8]) = vh;
            *((uint4*)&xl[r * 72 + cq * 8]) = vl;
        }
        for (int it = 0; it < 2; it++) {
            int r = it * 32 + (tid >> 3);
            int cq = tid & 7;
            uint4 vh = ((const uint4*)wt_h)[(size_t)(t0 + r) * (C_DIM / 8) + (c0 >> 3) + cq];
            uint4 vl = ((const uint4*)wt_l)[(size_t)(t0 + r) * (C_DIM / 8) + (c0 >> 3) + cq];
            *((uint4*)&wh[r * 72 + cq * 8]) = vh;
            *((uint4*)&wl[r * 72 + cq * 8]) = vl;
        }
        __syncthreads();
        for (int ks = 0; ks < 2; ks++) {
            int co = ks * 32 + quad * 8;
            short8 ah0 = *((const short8*)&xh[(mrow0 + l15) * 72 + co]);
            short8 ah1 = *((const short8*)&xh[(mrow0 + 16 + l15) * 72 + co]);
            short8 al0 = *((const short8*)&xl[(mrow0 + l15) * 72 + co]);
            short8 al1 = *((const short8*)&xl[(mrow0 + 16 + l15) * 72 + co]);
            short8 bh0 = *((const short8*)&wh[(ncol0 + l15) * 72 + co]);
            short8 bh1 = *((const short8*)&wh[(ncol0 + 16 + l15) * 72 + co]);
            short8 bl0 = *((const short8*)&wl[(ncol0 + l15) * 72 + co]);
            short8 bl1 = *((const short8*)&wl[(ncol0 + 16 + l15) * 72 + co]);
            acc[0][0] = __builtin_amdgcn_mfma_f32_16x16x32_bf16(ah0, bh0, acc[0][0], 0, 0, 0);
            acc[0][1] = __builtin_amdgcn_mfma_f32_16x16x32_bf16(ah0, bh1, acc[0][1], 0, 0, 0);
            acc[1][0] = __builtin_amdgcn_mfma_f32_16x16x32_bf16(ah1, bh0, acc[1][0], 0, 0, 0);
            acc[1][1] = __builtin_amdgcn_mfma_f32_16x16x32_bf16(ah1, bh1, acc[1][1], 0, 0, 0);
            acc[0][0] = __builtin_amdgcn_mfma_f32_16x16x32_bf16(ah0, bl0, acc[0][0], 0, 0, 0);
            acc[0][1] = __builtin_amdgcn_mfma_f32_16x16x32_bf16(ah0, bl1, acc[0][1], 0, 0, 0);
            acc[1][0] = __builtin_amdgcn_mfma_f32_16x16x32_bf16(ah1, bl0, acc[1][0], 0, 0, 0);
            acc[1][1] = __builtin_amdgcn_mfma_f32_16x16x32_bf16(ah1, bl1, acc[1][1], 0, 0, 0);
            acc[0][0] = __builtin_amdgcn_mfma_f32_16x16x32_bf16(al0, bh0, acc[0][0], 0, 0, 0);
            acc[0][1] = __builtin_amdgcn_mfma_f32_16x16x32_bf16(al0, bh1, acc[0][1], 0, 0, 0);
            acc[1][0] = __builtin_amdgcn_mfma_f32_16x16x32_bf16(al1, bh0, acc[1][0], 0, 0, 0);
            acc[1][1] = __builtin_amdgcn_mfma_f32_16x16x32_bf16(al1, bh1, acc[1][1], 0, 0, 0);
        }
        __syncthreads();
    }
    for (int i = 0; i < 2; i++)
        for (int j = 0; j < 2; j++)
            for (int r = 0; r < 4; r++) {
                int gr = m0 + mrow0 + i * 16 + quad * 4 + r;
                int gc = t0 + ncol0 + j * 16 + l15;
                if (gr < N_TOK) zbuf[(size_t)gr * MID + gc] = acc[i][j][r];
            }
}

// ---------------- z + b -> l2norm -> zn (in place) + zn_h -------------------
__global__ void k_znorm(float* __restrict__ zbuf, const float* __restrict__ b_down,
                        unsigned short* __restrict__ zn_h) {
    int n = blockIdx.x, t = threadIdx.x;
    float v = zbuf[(size_t)n * MID + t] + b_down[t];
    __shared__ float sb[256];
    sb[t] = v * v; __syncthreads();
    for (int s = 128; s > 0; s >>= 1) { if (t < s) sb[t] += sb[t + s]; __syncthreads(); }
    float nn = sqrtf(sb[0]);
    float o = v / fmaxf(nn, EPS_N);
    zbuf[(size_t)n * MID + t] = o;
    zn_h[(size_t)n * MID + t] = f2bf(o);
}

// ---------------- d-GEMM, two passes, no d materialization ------------------
// Operand LDS: [64][128] bf16 per matrix, XOR-swizzled columns
// (byte ^= (row&7)<<4) instead of +8 pad -> exactly 32768 B static LDS
// -> 5 blocks/CU (was 4 at 34816 B). Reg-staged writes, so swizzle is free.
// PASS 1: per-(row, col-tile) partials {min, st, s1, s2} -> part4 (nt store)
// PASS 2: probs -> out1 (nt f32x4), avg_probs column sums, candidates
template<int PASS>
__global__ __launch_bounds__(256) void k_dpass(const unsigned short* __restrict__ zn_h,
                                               const unsigned short* __restrict__ en_h,
                                               float* __restrict__ part4,
                                               const float* __restrict__ rs_m,
                                               const float* __restrict__ rs_ist,
                                               const float* __restrict__ rs_is1,
                                               float* __restrict__ ap_acc,
                                               float* __restrict__ out1,
                                               int* __restrict__ ccnt,
                                               int* __restrict__ cand) {
    __shared__ __align__(16) char smem[32768];
    char* atB = smem;            // A: 64 rows x 256 B (128 bf16), swizzled
    char* btB = smem + 16384;    // B: same
    int tid = threadIdx.x;
    int kt = blockIdx.x, mt = blockIdx.y;
    int m0 = mt * 64, k0c = kt * 64;
    int lane = tid & 63, wv = tid >> 6;
    int quad = lane >> 4, l15 = lane & 15;
    int mrow0 = (wv >> 1) * 32, ncol0 = (wv & 1) * 32;
    f32x4 acc[2][2] = {};

    for (int ch = 0; ch < 2; ch++) {
        int c0 = ch * 128;
        for (int it = 0; it < 4; it++) {
            int r = it * 16 + (tid >> 4);
            int cq = tid & 15;
            uint4 va = ((const uint4*)zn_h)[(size_t)(m0 + r) * (MID / 8) + (c0 >> 3) + cq];
            uint4 vb = ((const uint4*)en_h)[(size_t)(k0c + r) * (MID / 8) + (c0 >> 3) + cq];
            int boff = r * 256 + ((cq * 16) ^ ((r & 7) << 4));
            *((uint4*)(atB + boff)) = va;
            *((uint4*)(btB + boff)) = vb;
        }
        __syncthreads();
        for (int ks = 0; ks < 4; ks++) {
            int co = ks * 64 + quad * 16;    // byte col base within row
            int ra0 = mrow0 + l15,      ra1 = mrow0 + 16 + l15;
            int rb0 = ncol0 + l15,      rb1 = ncol0 + 16 + l15;
            short8 a0 = *((const short8*)(atB + ra0 * 256 + (co ^ ((ra0 & 7) << 4))));
            short8 a1 = *((const short8*)(atB + ra1 * 256 + (co ^ ((ra1 & 7) << 4))));
            short8 b0 = *((const short8*)(btB + rb0 * 256 + (co ^ ((rb0 & 7) << 4))));
            short8 b1 = *((const short8*)(btB + rb1 * 256 + (co ^ ((rb1 & 7) << 4))));
            acc[0][0] = __builtin_amdgcn_mfma_f32_16x16x32_bf16(a0, b0, acc[0][0], 0, 0, 0);
            acc[0][1] = __builtin_amdgcn_mfma_f32_16x16x32_bf16(a0, b1, acc[0][1], 0, 0, 0);
            acc[1][0] = __builtin_amdgcn_mfma_f32_16x16x32_bf16(a1, b0, acc[1][0], 0, 0, 0);
            acc[1][1] = __builtin_amdgcn_mfma_f32_16x16x32_bf16(a1, b1, acc[1][1], 0, 0, 0);
        }
        __syncthreads();
    }

    // ---- epilogue: reuse smem as fp32 d-tile [64][68] + small arrays ----
    float* sd = (float*)smem;                  // 64*68*4 = 17408 B
    float* lm = sd + 64 * 68;                  // 64
    float* lt = lm + 64;                       // 64
    float* l1 = lt + 64;                       // 64
    float* colacc = l1 + 64;                   // 256  (total 19200 B < 32768)

    if (PASS == 2) {
        if (tid < 64) {
            int gr = m0 + tid;
            bool okr = gr < N_TOK;
            lm[tid] = okr ? rs_m[gr] : 0.f;
            lt[tid] = okr ? rs_ist[gr] : 0.f;
            l1[tid] = okr ? rs_is1[gr] : 0.f;
        }
    }
    for (int i = 0; i < 2; i++)
        for (int j = 0; j < 2; j++)
            for (int r = 0; r < 4; r++) {
                int lr = mrow0 + i * 16 + quad * 4 + r;
                int lc = ncol0 + j * 16 + l15;
                int gc = k0c + lc;
                float dv = (gc < K_CODE) ? (2.f - 2.f * acc[i][j][r]) : 1e30f;
                sd[lr * 68 + lc] = dv;
            }
    __syncthreads();

    if (PASS == 1) {
        // 4 waves x 16 rows, 4 lanes/row, 16 values/lane
        int rloc = wv * 16 + (lane >> 2);
        const float* rowp = sd + rloc * 68 + (lane & 3) * 16;
        float vals[16];
        float vmin = 1e30f;
        #pragma unroll
        for (int i = 0; i < 16; i++) { vals[i] = rowp[i]; vmin = fminf(vmin, vals[i]); }
        vmin = fminf(vmin, __shfl_xor(vmin, 1));
        vmin = fminf(vmin, __shfl_xor(vmin, 2));
        float st = 0.f, s1 = 0.f, s2 = 0.f;
        #pragma unroll
        for (int i = 0; i < 16; i++) {
            float dd = vmin - vals[i];
            st += __expf(dd * INV_TEMP);
            float te = dd * INV_ETEMP;
            float e = __expf(te);
            s1 += e; s2 += e * te;
        }
        st += __shfl_xor(st, 1); st += __shfl_xor(st, 2);
        s1 += __shfl_xor(s1, 1); s1 += __shfl_xor(s1, 2);
        s2 += __shfl_xor(s2, 1); s2 += __shfl_xor(s2, 2);
        if ((lane & 3) == 0) {
            int gr = m0 + rloc;
            if (gr < N_TOK)
                nt_store4(part4 + ((size_t)gr * N_KT + kt) * 4, vmin, st, s1, s2);
        }
    } else {
        // phase A: avg_probs column sums
        int col = tid & 63, rq = tid >> 6;
        float ce = 0.f;
        #pragma unroll
        for (int r16 = 0; r16 < 16; r16++) {
            int lr = rq * 16 + r16;
            float dv = sd[lr * 68 + col];
            ce += __expf((lm[lr] - dv) * INV_ETEMP) * l1[lr];
        }
        colacc[rq * 64 + col] = ce;
        __syncthreads();
        if (tid < 64) {
            float s = colacc[tid] + colacc[64 + tid] + colacc[128 + tid] + colacc[192 + tid];
            int gc = k0c + tid;
            if (gc < K_CODE) atomicAdd(&ap_acc[gc], s);
        }
        // phase B: probs store (nt f32x4) + element-level candidate collection
        #pragma unroll
        for (int it = 0; it < 4; it++) {
            int idx = it * 256 + tid;
            int lr = idx >> 4, c4 = idx & 15;
            int gr = m0 + lr;
            if (gr >= N_TOK) continue;
            int gc = k0c + c4 * 4;
            if (gc >= K_CODE) continue;           // K_CODE % 4 == 0: fully in or out
            float4 v = *((const float4*)(sd + lr * 68 + c4 * 4));
            float mm = lm[lr], tt = lt[lr];
            float thr = mm + MARGIN;
            if (v.x <= thr) { int p = atomicAdd(&ccnt[gr], 1); if (p < CAND_CAP) cand[gr * CAND_CAP + p] = gc + 0; }
            if (v.y <= thr) { int p = atomicAdd(&ccnt[gr], 1); if (p < CAND_CAP) cand[gr * CAND_CAP + p] = gc + 1; }
            if (v.z <= thr) { int p = atomicAdd(&ccnt[gr], 1); if (p < CAND_CAP) cand[gr * CAND_CAP + p] = gc + 2; }
            if (v.w <= thr) { int p = atomicAdd(&ccnt[gr], 1); if (p < CAND_CAP) cand[gr * CAND_CAP + p] = gc + 3; }
            nt_store4(out1 + (size_t)gr * K_CODE + gc,
                      __expf((mm - v.x) * INV_TEMP) * tt,
                      __expf((mm - v.y) * INV_TEMP) * tt,
                      __expf((mm - v.z) * INV_TEMP) * tt,
                      __expf((mm - v.w) * INV_TEMP) * tt);
        }
    }
}

// ---------------- combine 140 tile-partials per row -------------------------
__global__ void k_combine(const float4* __restrict__ part4,
                          float* __restrict__ rs_m, float* __restrict__ rs_ist,
                          float* __restrict__ rs_is1,
                          float* __restrict__ acc4) {
    int sub = threadIdx.x >> 6;
    int row = blockIdx.x * 4 + sub;
    int l = threadIdx.x & 63;
    float4 pv[3];
    float m = 1e30f;
    #pragma unroll
    for (int c = 0; c < 3; c++) {
        int t = l + c * 64;
        pv[c] = (t < N_KT) ? part4[(size_t)row * N_KT + t] : make_float4(1e30f, 0.f, 0.f, 0.f);
        m = fminf(m, pv[c].x);
    }
    #pragma unroll
    for (int s = 1; s < 64; s <<= 1) m = fminf(m, __shfl_xor(m, s));
    float st = 0.f, s1 = 0.f, s2 = 0.f;
    #pragma unroll
    for (int c = 0; c < 3; c++) {
        float mb = pv[c].x;
        int t = l + c * 64;
        if (t < N_KT && mb < 1e29f) {
            float dT = (m - mb) * INV_TEMP;
            st += __expf(dT) * pv[c].y;
            float dE = (m - mb) * INV_ETEMP;
            float e = __expf(dE);
            s1 += e * pv[c].z;
            s2 += e * (pv[c].w + dE * pv[c].z);
        }
    }
    #pragma unroll
    for (int s = 1; s < 64; s <<= 1) {
        st += __shfl_xor(st, s);
        s1 += __shfl_xor(s1, s);
        s2 += __shfl_xor(s2, s);
    }
    if (l == 0) {
        rs_m[row] = m;
        rs_ist[row] = 1.f / st;
        rs_is1[row] = 1.f / s1;
        atomicAdd(&acc4[1], s2 / s1 - __logf(s1));
    }
}

// ---------------- exact fp32 argmin over candidates + out0 fused ------------
__global__ void k_refine(const float* __restrict__ zn, const float* __restrict__ en,
                         const int* __restrict__ ccnt, const int* __restrict__ cand,
                         int* __restrict__ idxb, int* __restrict__ used,
                         float* __restrict__ acc4, float* __restrict__ out0) {
    int n = blockIdx.x * 4 + (threadIdx.x >> 6);
    int lane = threadIdx.x & 63;
    if (n >= N_TOK) return;
    int cnt = ccnt[n];
    if (cnt > CAND_CAP) cnt = CAND_CAP;
    float4 a = ((const float4*)(zn + (size_t)n * MID))[lane];
    float best = 1e30f; int bj = K_CODE;
    for (int c = 0; c < cnt; c++) {
        int code = cand[n * CAND_CAP + c];
        float4 b = ((const float4*)(en + (size_t)code * MID))[lane];
        float s = a.x * b.x + a.y * b.y + a.z * b.z + a.w * b.w;
        #pragma unroll
        for (int off = 1; off < 64; off <<= 1) s += __shfl_xor(s, off);
        float dist = 2.f - 2.f * s;
        if (dist < best || (dist == best && code < bj)) { best = dist; bj = code; }
    }
    float4 b = ((const float4*)(en + (size_t)bj * MID))[lane];
    nt_store4(out0 + (size_t)n * MID + lane * 4, b.x, b.y, b.z, b.w);
    float dx = b.x - a.x, dy = b.y - a.y, dz = b.z - a.z, dw = b.w - a.w;
    float sq = dx * dx + dy * dy + dz * dz + dw * dw;
    #pragma unroll
    for (int off = 32; off > 0; off >>= 1) sq += __shfl_down(sq, off);
    if (lane == 0) {
        idxb[n] = bj;
        used[bj] = 1;
        atomicAdd(&acc4[0], sq);
    }
}

// ---------------- final scalars ---------------------------------------------
__global__ void k_scal(const int* __restrict__ used, const float* __restrict__ ap_acc,
                       const float* __restrict__ acc4, float* __restrict__ outs) {
    int t = threadIdx.x;
    float uSum = 0.f, aeSum = 0.f;
    for (int k = t; k < K_CODE; k += 256) {
        uSum += (float)used[k];
        float ap = ap_acc[k] * (1.0f / (float)N_TOK);
        aeSum += ap * __logf(ap + 1e-5f);
    }
    __shared__ float sb[256];
    sb[t] = uSum; __syncthreads();
    for (int s = 128; s > 0; s >>= 1) { if (t < s) sb[t] += sb[t + s]; __syncthreads(); }
    uSum = sb[0];
    __syncthreads(); sb[t] = aeSum; __syncthreads();
    for (int s = 128; s > 0; s >>= 1) { if (t < s) sb[t] += sb[t + s]; __syncthreads(); }
    aeSum = sb[0];
    if (t == 0) {
        outs[0] = uSum / (float)K_CODE;
        float vq = acc4[0] / (float)((size_t)N_TOK * MID);
        outs[1] = vq;
        outs[2] = vq;
        outs[3] = -(acc4[1] / (float)N_TOK) + aeSum;
    }
}

extern "C" void kernel_launch(void* const* d_in, const int* in_sizes, int n_in,
                              void* d_out, int out_size, void* d_ws, size_t ws_size,
                              hipStream_t stream) {
    const float* x   = (const float*)d_in[0];
    const float* W   = (const float*)d_in[1];
    const float* b   = (const float*)d_in[2];
    const float* emb = (const float*)d_in[3];

    float* out  = (float*)d_out;
    float* out0 = out;                                                  // [7200*256]
    float* out1 = out + (size_t)N_TOK * MID;                            // probs
    float* outs = out + (size_t)N_TOK * MID + (size_t)N_TOK * K_CODE;   // 4 scalars

    char* w = (char*)d_ws;
    size_t off = 0;
    auto carve = [&](size_t bytes) { void* p = w + off; off += (bytes + 255) & ~(size_t)255; return p; };
    float*          zn    = (float*)         carve((size_t)N_PAD * MID * 4);
    float*          en    = (float*)         carve((size_t)K_PAD * MID * 4);
    unsigned short* zn_h  = (unsigned short*)carve((size_t)N_PAD * MID * 2);
    unsigned short* en_h  = (unsigned short*)carve((size_t)K_PAD * MID * 2);
    unsigned short* wt_h  = (unsigned short*)carve((size_t)MID * C_DIM * 2);
    unsigned short* wt_l  = (unsigned short*)carve((size_t)MID * C_DIM * 2);
    unsigned short* xh_g  = (unsigned short*)carve((size_t)N_TOK * C_DIM * 2);
    unsigned short* xl_g  = (unsigned short*)carve((size_t)N_TOK * C_DIM * 2);
    float*          part4 = (float*)         carve((size_t)N_TOK * N_KT * 16);
    float*          rs_m  = (float*)         carve((size_t)N_TOK * 4);
    float*          rs_ist= (float*)         carve((size_t)N_TOK * 4);
    float*          rs_is1= (float*)         carve((size_t)N_TOK * 4);
    int*            ccnt  = (int*)           carve((size_t)N_TOK * 4);
    int*            cand  = (int*)           carve((size_t)N_TOK * CAND_CAP * 4);
    int*            idxb  = (int*)           carve((size_t)N_TOK * 4);
    float*          ap_acc= (float*)         carve((size_t)K_CODE * 4);
    int*            used  = (int*)           carve((size_t)K_CODE * 4);
    float*          acc4  = (float*)         carve(16);
    (void)ws_size; (void)in_sizes; (void)n_in; (void)out_size;

    k_prep   <<<K_CODE + 768 + 5400 + 35, 256, 0, stream>>>(emb, en, en_h, W, wt_h, wt_l,
                                                            x, xh_g, xl_g,
                                                            ap_acc, used, acc4, ccnt);
    k_zgemm  <<<dim3(4, 113), 256, 0, stream>>>(xh_g, xl_g, wt_h, wt_l, zn);
    k_znorm  <<<N_TOK, 256, 0, stream>>>(zn, b, zn_h);
    k_dpass<1><<<dim3(N_KT, 113), 256, 0, stream>>>(zn_h, en_h, part4, rs_m, rs_ist, rs_is1, ap_acc, out1, ccnt, cand);
    k_combine<<<N_TOK / 4, 256, 0, stream>>>((const float4*)part4, rs_m, rs_ist, rs_is1, acc4);
    k_dpass<2><<<dim3(N_KT, 113), 256, 0, stream>>>(zn_h, en_h, part4, rs_m, rs_ist, rs_is1, ap_acc, out1, ccnt, cand);
    k_refine <<<N_TOK / 4, 256, 0, stream>>>(zn, en, ccnt, cand, idxb, used, acc4, out0);
    k_scal   <<<1, 256, 0, stream>>>(used, ap_acc, acc4, outs);
}